// Round 2
// baseline (2337.164 us; speedup 1.0000x reference)
//
#include <hip/hip_runtime.h>
#include <hip/hip_bf16.h>

// Shapes (fixed): B=16, L=1024, C=512, P=64, H=8, DK=64, MRD=7
#define BI   16
#define LSEQ 1024
#define CDIM 512
#define PDIM 64
#define HH   8
#define DKK  64

typedef __hip_bfloat16 bf16;
typedef unsigned short u16;

// rel-pos bucket boundaries: bucket t covers |l-m| in [dlo[t], dhi[t]]
__constant__ int c_dlo[15] = {0,1,2,3,4,5,6,7, 9,11,15,23,39, 71,135};
__constant__ int c_dhi[15] = {0,1,2,3,4,5,6,8,10,14,22,38,70,134,1023};

__device__ __forceinline__ float b2f(u16 u) {
    union { unsigned int i; float f; } c; c.i = ((unsigned int)u) << 16; return c.f;
}
__device__ __forceinline__ u16 f2bu(float v) {
    bf16 h = __float2bfloat16(v);
    return *(u16*)&h;
}
// dynamic-dtype loads: f=1 -> fp32, f=0 -> bf16
__device__ __forceinline__ float ldDyn(const void* p, size_t i, int f) {
    return f ? ((const float*)p)[i] : b2f(((const u16*)p)[i]);
}
__device__ __forceinline__ void ld4Dyn(const void* p, size_t i, int f, float* o) {
    if (f) { float4 v = *(const float4*)((const float*)p + i);
             o[0]=v.x; o[1]=v.y; o[2]=v.z; o[3]=v.w; }
    else   { ushort4 u = *(const ushort4*)((const u16*)p + i);
             o[0]=b2f(u.x); o[1]=b2f(u.y); o[2]=b2f(u.z); o[3]=b2f(u.w); }
}

__device__ __forceinline__ float wsum(float v) {
    #pragma unroll
    for (int o = 32; o; o >>= 1) v += __shfl_xor(v, o, 64);
    return v;
}
__device__ __forceinline__ float wmax(float v) {
    #pragma unroll
    for (int o = 32; o; o >>= 1) v = fmaxf(v, __shfl_xor(v, o, 64));
    return v;
}

// ---------------------------------------------------------------------------
// dtype detect: if inputs are packed bf16, the low 16 bits of each 32-bit word
// of qx are themselves plausible N(0,1) bf16 values; if fp32, they're random
// mantissa bits (~6% plausible). flag: 0 = bf16, 1 = fp32.
// ---------------------------------------------------------------------------
__global__ void k_detect(const unsigned int* __restrict__ qw, int* __restrict__ flag) {
    __shared__ int cnt;
    if (threadIdx.x == 0) cnt = 0;
    __syncthreads();
    int local = 0;
    for (int i = threadIdx.x; i < 4096; i += 256) {
        float fv = b2f((u16)(qw[i] & 0xFFFFu));
        float af = fabsf(fv);
        if (fv == 0.0f || (af >= 0.0009765625f && af <= 32.0f)) local++;
    }
    atomicAdd(&cnt, local);
    __syncthreads();
    if (threadIdx.x == 0) flag[0] = (cnt >= 2048) ? 0 : 1;
}

// ---------------------------------------------------------------------------
// Tiled GEMM: C[M,N] = op(A[M,K] @ W[K,N] + bias)
// aKind: 0=bf16, 1=f32, 2=dynamic(flag). W and bias always dynamic.
// mode 0: C = acc+bias ; 1: C = gelu(acc+bias) ; 2: C(f32) += acc
// outBf (modes 0/1): 1 -> bf16 C, 0 -> f32 C.
// wOff/bOff: element offsets into W/bias (dtype-width-safe chunking).
// ---------------------------------------------------------------------------
__global__ __launch_bounds__(256) void gemm_k(
    const void* __restrict__ A, const void* __restrict__ W, const void* __restrict__ bias,
    void* __restrict__ Cc, const int* __restrict__ flag,
    int M, int N, int K, int lda, int ldw, int ldc,
    size_t wOff, size_t bOff, int aKind, int mode, int outBf)
{
    const int fd = flag[0];
    const int fA = (aKind == 2) ? fd : aKind;
    __shared__ float As[16][65];   // [k][m], padded
    __shared__ float Bs[16][64];   // [k][n]
    const int n0 = blockIdx.x * 64;
    const int m0 = blockIdx.y * 64;
    const int tid = threadIdx.x;
    const int tx = tid & 15, ty = tid >> 4;
    float acc[4][4] = {};

    for (int k0 = 0; k0 < K; k0 += 16) {
        {   // A tile: 64 m x 16 k, each thread 4 consecutive k
            int e = tid * 4, m = e >> 4, kk = e & 15;
            float t4[4]; ld4Dyn(A, (size_t)(m0 + m) * lda + k0 + kk, fA, t4);
            As[kk+0][m] = t4[0]; As[kk+1][m] = t4[1]; As[kk+2][m] = t4[2]; As[kk+3][m] = t4[3];
        }
        {   // W tile: 16 k x 64 n, each thread 4 consecutive n
            int e = tid * 4, kk = e >> 6, n = e & 63;
            float t4[4]; ld4Dyn(W, wOff + (size_t)(k0 + kk) * ldw + n0 + n, fd, t4);
            Bs[kk][n+0] = t4[0]; Bs[kk][n+1] = t4[1]; Bs[kk][n+2] = t4[2]; Bs[kk][n+3] = t4[3];
        }
        __syncthreads();
        #pragma unroll
        for (int kk = 0; kk < 16; ++kk) {
            float a[4], b[4];
            #pragma unroll
            for (int i = 0; i < 4; ++i) a[i] = As[kk][ty*4 + i];
            #pragma unroll
            for (int j = 0; j < 4; ++j) b[j] = Bs[kk][tx*4 + j];
            #pragma unroll
            for (int i = 0; i < 4; ++i)
                #pragma unroll
                for (int j = 0; j < 4; ++j) acc[i][j] += a[i] * b[j];
        }
        __syncthreads();
    }

    #pragma unroll
    for (int i = 0; i < 4; ++i) {
        size_t m = (size_t)m0 + ty*4 + i;
        #pragma unroll
        for (int j = 0; j < 4; ++j) {
            int n = n0 + tx*4 + j;
            float v = acc[i][j];
            if (mode == 2) {
                ((float*)Cc)[m * ldc + n] += v;
            } else {
                v += ldDyn(bias, bOff + n, fd);
                if (mode == 1) v = 0.5f * v * (1.0f + erff(v * 0.70710678118654752f));
                if (outBf) ((u16*)Cc)[m * ldc + n] = f2bu(v);
                else       ((float*)Cc)[m * ldc + n] = v;
            }
        }
    }
}

// ---------------------------------------------------------------------------
// Softmax over L (axis=1) per (b,p) + inclusive prefix scan -> cum.
// psc may alias pAlpha (each element is read then rewritten by its own thread).
// ---------------------------------------------------------------------------
__global__ __launch_bounds__(256) void k_softscan(
    const float* __restrict__ psc, const int* __restrict__ maskPAD,
    float* __restrict__ pAlpha, float* __restrict__ cum)
{
    const int b = blockIdx.x >> 6;
    const int p = blockIdx.x & 63;
    const int tid = threadIdx.x;
    __shared__ float s0[1024], s1[1024];
    __shared__ float redA[4], redB[4];

    float acc[4];
    #pragma unroll
    for (int r = 0; r < 4; ++r) {
        int m = tid + r * 256;
        float a = psc[((size_t)b * LSEQ + m) * PDIM + p];
        if (maskPAD[(size_t)b * LSEQ * LSEQ + m] == 0) a = -32768.0f;
        acc[r] = a;
    }
    float mx = fmaxf(fmaxf(acc[0], acc[1]), fmaxf(acc[2], acc[3]));
    mx = wmax(mx);
    if ((tid & 63) == 0) redA[tid >> 6] = mx;
    __syncthreads();
    mx = fmaxf(fmaxf(redA[0], redA[1]), fmaxf(redA[2], redA[3]));

    float e[4], ls = 0.f;
    #pragma unroll
    for (int r = 0; r < 4; ++r) { e[r] = expf(acc[r] - mx); ls += e[r]; }
    ls = wsum(ls);
    if ((tid & 63) == 0) redB[tid >> 6] = ls;
    __syncthreads();
    float inv = 1.0f / (redB[0] + redB[1] + redB[2] + redB[3]);

    #pragma unroll
    for (int r = 0; r < 4; ++r) {
        int m = tid + r * 256;
        float pa = e[r] * inv;
        pAlpha[((size_t)b * LSEQ + m) * PDIM + p] = pa;
        s0[m] = pa;
    }
    __syncthreads();

    float* src = s0; float* dst = s1;
    for (int off = 1; off < 1024; off <<= 1) {
        #pragma unroll
        for (int r = 0; r < 4; ++r) {
            int i = tid + r * 256;
            float v = src[i];
            if (i >= off) v += src[i - off];
            dst[i] = v;
        }
        __syncthreads();
        float* t = src; src = dst; dst = t;
    }
    size_t cb = ((size_t)b * PDIM + p) * (LSEQ + 1);
    if (tid == 0) cum[cb] = 0.f;
    #pragma unroll
    for (int r = 0; r < 4; ++r) {
        int i = tid + r * 256;
        cum[cb + i + 1] = src[i];
    }
}

// ---------------------------------------------------------------------------
// kxp[b,p,c] = sum_m pAlpha[b,m,p] * kx[b,m,c]  (and vxp from vx)
// ---------------------------------------------------------------------------
__global__ __launch_bounds__(512) void k_pool(
    const void* __restrict__ kx, const void* __restrict__ vx,
    const float* __restrict__ pAlpha, float* __restrict__ kxp, float* __restrict__ vxp,
    const int* __restrict__ flag)
{
    const int fd = flag[0];
    const int b  = blockIdx.x >> 4;
    const int p0 = (blockIdx.x & 15) * 4;
    const int c  = threadIdx.x;
    float aK[4] = {0,0,0,0}, aV[4] = {0,0,0,0};
    for (int m = 0; m < LSEQ; ++m) {
        size_t idx = ((size_t)b * LSEQ + m) * CDIM + c;
        float kv = ldDyn(kx, idx, fd);
        float vv = ldDyn(vx, idx, fd);
        const float* pa = pAlpha + ((size_t)b * LSEQ + m) * PDIM + p0;
        #pragma unroll
        for (int j = 0; j < 4; ++j) { float a = pa[j]; aK[j] += a * kv; aV[j] += a * vv; }
    }
    #pragma unroll
    for (int j = 0; j < 4; ++j) {
        kxp[((size_t)b * PDIM + p0 + j) * CDIM + c] = aK[j];
        vxp[((size_t)b * PDIM + p0 + j) * CDIM + c] = aV[j];
    }
}

// ---------------------------------------------------------------------------
// Attention: one block per (b,l), 512 threads. q read from qz (bf16), z
// written back in place (each element owned by exactly one thread).
// ---------------------------------------------------------------------------
__global__ __launch_bounds__(512) void k_attn(
    u16* __restrict__ qz, const float* __restrict__ kb, const float* __restrict__ vb,
    const float* __restrict__ cum, const void* __restrict__ embK, const void* __restrict__ embB,
    const int* __restrict__ flag)
{
    const int fd = flag[0];
    const int b = blockIdx.x >> 10;
    const int l = blockIdx.x & 1023;
    const int tid = threadIdx.x;
    __shared__ float qrow[CDIM];
    __shared__ float S[15][PDIM];
    __shared__ float al[HH][PDIM];
    __shared__ float eK[15 * HH], eB[15 * HH];

    const size_t rowOff = ((size_t)b * LSEQ + l) * CDIM;
    qrow[tid] = b2f(qz[rowOff + tid]);
    if (tid < 15 * HH) { eK[tid] = ldDyn(embK, tid, fd); eB[tid] = ldDyn(embB, tid, fd); }

    for (int idx = tid; idx < 15 * PDIM; idx += 512) {
        int t = idx >> 6, p = idx & 63;
        const float* cc = cum + ((size_t)b * PDIM + p) * (LSEQ + 1);
        float s;
        if (t == 0) {
            s = cc[l + 1] - cc[l];
        } else {
            s = 0.f;
            int hi = l - c_dlo[t];
            int lo = l - c_dhi[t]; if (lo < 0) lo = 0;
            if (hi >= lo) s += cc[hi + 1] - cc[lo];
            lo = l + c_dlo[t];
            hi = l + c_dhi[t]; if (hi > LSEQ - 1) hi = LSEQ - 1;
            if (lo <= hi) s += cc[hi + 1] - cc[lo];
        }
        S[t][p] = s;
    }
    __syncthreads();

    const int h = tid >> 6, p = tid & 63;   // wave h, lane p
    const float* kr = kb + ((size_t)b * PDIM + p) * CDIM + h * DKK;
    const float* qh = qrow + h * DKK;
    float raw = 0.f;
    #pragma unroll 8
    for (int d = 0; d < DKK; ++d) raw += qh[d] * kr[d];

    float kbm = 0.f, bbm = 0.f;
    #pragma unroll
    for (int t = 0; t < 15; ++t) {
        float sv = S[t][p];
        kbm += eK[t * HH + h] * sv;
        bbm += eB[t * HH + h] * sv;
    }
    float sc = raw * 0.125f * kbm + bbm;

    float mx = wmax(sc);
    float e = expf(sc - mx);
    float ssum = wsum(e);
    al[h][p] = e / ssum;
    __syncthreads();

    float z = 0.f;
    const float* vcol = vb + (size_t)b * PDIM * CDIM + tid;
    #pragma unroll 8
    for (int pp = 0; pp < PDIM; ++pp) z += al[h][pp] * vcol[(size_t)pp * CDIM];
    qz[rowOff + tid] = f2bu(z);
}

// ---------------------------------------------------------------------------
// LayerNorm: y = LN(a (+ badd)) * g + be ; optional out2 = y + bias2 (f32)
// aKind/outKind: 0=bf16, 1=f32, 2=dynamic
// ---------------------------------------------------------------------------
__global__ __launch_bounds__(512) void k_ln(
    const void* __restrict__ a, const u16* __restrict__ badd,
    const void* __restrict__ g, const void* __restrict__ be, const int* __restrict__ flag,
    void* __restrict__ out, float* __restrict__ out2, const void* __restrict__ bias2,
    int aKind, int outKind)
{
    const int fd = flag[0];
    const int fA = (aKind == 2) ? fd : aKind;
    const int fO = (outKind == 2) ? fd : outKind;
    const size_t row = blockIdx.x;
    const int c = threadIdx.x;
    float x = ldDyn(a, row * CDIM + c, fA);
    if (badd) x += b2f(badd[row * CDIM + c]);

    __shared__ float rA[8], rB[8];
    float s = wsum(x);
    if ((c & 63) == 0) rA[c >> 6] = s;
    __syncthreads();
    float tot = 0.f;
    #pragma unroll
    for (int w = 0; w < 8; ++w) tot += rA[w];
    float mu = tot * (1.0f / 512.0f);
    float dv = x - mu;
    float s2 = wsum(dv * dv);
    if ((c & 63) == 0) rB[c >> 6] = s2;
    __syncthreads();
    float v2 = 0.f;
    #pragma unroll
    for (int w = 0; w < 8; ++w) v2 += rB[w];
    float y = dv * rsqrtf(v2 * (1.0f / 512.0f) + 1e-5f) * ldDyn(g, c, fd) + ldDyn(be, c, fd);
    if (fO) ((float*)out)[row * CDIM + c] = y;
    else    ((u16*)out)[row * CDIM + c] = f2bu(y);
    if (out2) out2[row * CDIM + c] = y + ldDyn(bias2, c, fd);
}

// ---------------------------------------------------------------------------
extern "C" void kernel_launch(void* const* d_in, const int* in_sizes, int n_in,
                              void* d_out, int out_size, void* d_ws, size_t ws_size,
                              hipStream_t stream)
{
    (void)in_sizes; (void)n_in; (void)out_size; (void)ws_size;
    const void* qx   = d_in[0];
    const void* kx   = d_in[1];
    const void* vx   = d_in[2];
    const int*  mask = (const int*)d_in[3];
    const void* Wp   = d_in[4];
    const void* bp   = d_in[5];
    const void* WQ   = d_in[6];
    const void* bQ   = d_in[7];
    const void* WK   = d_in[8];
    const void* bK   = d_in[9];
    const void* WV   = d_in[10];
    const void* bV   = d_in[11];
    const void* WO   = d_in[12];
    const void* bO   = d_in[13];
    const void* embK = d_in[14];
    const void* embB = d_in[15];
    const void* l1g  = d_in[16];
    const void* l1b  = d_in[17];
    const void* l2g  = d_in[18];
    const void* l2b  = d_in[19];
    const void* W1   = d_in[20];
    const void* b1   = d_in[21];
    const void* W2   = d_in[22];
    const void* b2   = d_in[23];

    // workspace map (float-element offsets from base); total ~100.7 MB
    float* ws   = (float*)d_ws;
    int* flag   = (int*)d_ws;                    // [0]
    float* pAlpha = ws + 64;                     // 1,048,576 f32 (also pScore)
    float* cum  = ws + 64 + 1048576;             // 1,049,600 f32
    float* kxp  = ws + 64 + 2098176;             //   524,288 f32
    float* vxp  = ws + 64 + 2622464;             //   524,288 f32
    float* kb   = ws + 64 + 3146752;             //   524,288 f32
    float* vb   = ws + 64 + 3671040;             //   524,288 f32
    float* pre2 = ws + 64 + 4195328;             // 8,388,608 f32
    u16* qz     = (u16*)(ws + 64 + 12583936);    // 8,388,608 bf16 (q -> z -> z1)
    u16* zo     = (u16*)(ws + 64 + 16778240);    // 8,388,608 bf16
    u16* hch    = (u16*)(ws + 64 + 20972544);    // 8,388,608 bf16 (FFN hidden chunk)

    const int MROW = BI * LSEQ;                  // 16384

    // 0) dtype detection -> flag
    k_detect<<<dim3(1), dim3(256), 0, stream>>>((const unsigned int*)qx, flag);

    // 1) pScore = vx @ Wp + bp  -> pAlpha region (f32)
    gemm_k<<<dim3(1, MROW / 64), dim3(256), 0, stream>>>(
        vx, Wp, bp, pAlpha, flag, MROW, PDIM, CDIM, CDIM, PDIM, PDIM, 0, 0, 2, 0, 0);
    // 2) softmax over L + prefix scan (in-place on pAlpha) -> cum
    k_softscan<<<dim3(BI * PDIM), dim3(256), 0, stream>>>(pAlpha, mask, pAlpha, cum);
    // 3) pooling -> kxp, vxp (f32)
    k_pool<<<dim3(BI * 16), dim3(512), 0, stream>>>(kx, vx, pAlpha, kxp, vxp, flag);
    // 4) projections: q (bf16 -> qz), k/v (f32)
    gemm_k<<<dim3(8, MROW / 64), dim3(256), 0, stream>>>(
        qx, WQ, bQ, qz, flag, MROW, CDIM, CDIM, CDIM, CDIM, CDIM, 0, 0, 2, 0, 1);
    gemm_k<<<dim3(8, 16), dim3(256), 0, stream>>>(
        kxp, WK, bK, kb, flag, BI * PDIM, CDIM, CDIM, CDIM, CDIM, CDIM, 0, 0, 1, 0, 0);
    gemm_k<<<dim3(8, 16), dim3(256), 0, stream>>>(
        vxp, WV, bV, vb, flag, BI * PDIM, CDIM, CDIM, CDIM, CDIM, CDIM, 0, 0, 1, 0, 0);
    // 5) attention: z overwrites q in qz
    k_attn<<<dim3(BI * LSEQ), dim3(512), 0, stream>>>(qz, kb, vb, cum, embK, embB, flag);
    // 6) zo = z @ WO + bO (bf16)
    gemm_k<<<dim3(8, MROW / 64), dim3(256), 0, stream>>>(
        qz, WO, bO, zo, flag, MROW, CDIM, CDIM, CDIM, CDIM, CDIM, 0, 0, 0, 0, 1);
    // 7) LN1: z1 = LN(vx + zo) -> qz (bf16) ; pre2 = z1 + b2 (f32)
    k_ln<<<dim3(MROW), dim3(512), 0, stream>>>(
        vx, zo, l1g, l1b, flag, qz, pre2, b2, 2, 0);
    // 8) FFN in 4 hidden-column chunks of 512
    for (int j = 0; j < 4; ++j) {
        gemm_k<<<dim3(8, MROW / 64), dim3(256), 0, stream>>>(
            qz, W1, b1, hch, flag, MROW, 512, CDIM, CDIM, 2048, 512,
            (size_t)j * 512, (size_t)j * 512, 0, 1, 1);
        gemm_k<<<dim3(8, MROW / 64), dim3(256), 0, stream>>>(
            hch, W2, nullptr, pre2, flag, MROW, CDIM, 512, 512, CDIM, CDIM,
            (size_t)j * 512 * 512, 0, 0, 2, 0);
    }
    // 9) LN2 -> d_out (dtype follows detection)
    k_ln<<<dim3(MROW), dim3(512), 0, stream>>>(
        pre2, nullptr, l2g, l2b, flag, d_out, nullptr, nullptr, 1, 2);
}

// Round 3
// 1222.854 us; speedup vs baseline: 1.9112x; 1.9112x over previous
//
#include <hip/hip_runtime.h>
#include <hip/hip_bf16.h>

// Shapes (fixed): B=16, L=1024, C=512, P=64, H=8, DK=64, MRD=7
#define BI   16
#define LSEQ 1024
#define CDIM 512
#define PDIM 64
#define HH   8
#define DKK  64

typedef __hip_bfloat16 bf16;
typedef unsigned short u16;
typedef __attribute__((ext_vector_type(8))) short bf16x8;
typedef __attribute__((ext_vector_type(4))) float f32x4;

// rel-pos bucket boundaries: bucket t covers |l-m| in [dlo[t], dhi[t]]
__constant__ int c_dlo[15] = {0,1,2,3,4,5,6,7, 9,11,15,23,39, 71,135};
__constant__ int c_dhi[15] = {0,1,2,3,4,5,6,8,10,14,22,38,70,134,1023};

__device__ __forceinline__ float b2f(u16 u) {
    union { unsigned int i; float f; } c; c.i = ((unsigned int)u) << 16; return c.f;
}
__device__ __forceinline__ u16 f2bu(float v) {
    bf16 h = __float2bfloat16(v);
    return *(u16*)&h;
}
// dynamic-dtype loads: f=1 -> fp32, f=0 -> bf16
__device__ __forceinline__ float ldDyn(const void* p, size_t i, int f) {
    return f ? ((const float*)p)[i] : b2f(((const u16*)p)[i]);
}
__device__ __forceinline__ void ld4Dyn(const void* p, size_t i, int f, float* o) {
    if (f) { float4 v = *(const float4*)((const float*)p + i);
             o[0]=v.x; o[1]=v.y; o[2]=v.z; o[3]=v.w; }
    else   { ushort4 u = *(const ushort4*)((const u16*)p + i);
             o[0]=b2f(u.x); o[1]=b2f(u.y); o[2]=b2f(u.z); o[3]=b2f(u.w); }
}

__device__ __forceinline__ float wsum(float v) {
    #pragma unroll
    for (int o = 32; o; o >>= 1) v += __shfl_xor(v, o, 64);
    return v;
}
__device__ __forceinline__ float wmax(float v) {
    #pragma unroll
    for (int o = 32; o; o >>= 1) v = fmaxf(v, __shfl_xor(v, o, 64));
    return v;
}

// ---------------------------------------------------------------------------
// dtype detect: bf16-packed inputs have plausible bf16 values in the low 16
// bits of each word (~99%); fp32 low halves are random mantissa bits (~6%).
// flag: 0 = bf16, 1 = fp32.
// ---------------------------------------------------------------------------
__global__ void k_detect(const unsigned int* __restrict__ qw, int* __restrict__ flag) {
    __shared__ int cnt;
    if (threadIdx.x == 0) cnt = 0;
    __syncthreads();
    int local = 0;
    for (int i = threadIdx.x; i < 4096; i += 256) {
        float fv = b2f((u16)(qw[i] & 0xFFFFu));
        float af = fabsf(fv);
        if (fv == 0.0f || (af >= 0.0009765625f && af <= 32.0f)) local++;
    }
    atomicAdd(&cnt, local);
    __syncthreads();
    if (threadIdx.x == 0) flag[0] = (cnt >= 2048) ? 0 : 1;
}

// ---------------------------------------------------------------------------
// convert dyn -> bf16 flat (n multiple of 4)
// ---------------------------------------------------------------------------
__global__ __launch_bounds__(256) void k_cvt(
    const void* __restrict__ src, u16* __restrict__ dst, const int* __restrict__ flag, int n)
{
    const int fd = flag[0];
    int i = (blockIdx.x * 256 + threadIdx.x) * 4;
    if (i >= n) return;
    float t[4]; ld4Dyn(src, i, fd, t);
    ushort4 o; o.x = f2bu(t[0]); o.y = f2bu(t[1]); o.z = f2bu(t[2]); o.w = f2bu(t[3]);
    *(ushort4*)(dst + i) = o;
}

// ---------------------------------------------------------------------------
// transpose dyn W[Kd][Nd] -> bf16 WT[Nd][Kd]; Kd,Nd multiples of 32
// ---------------------------------------------------------------------------
__global__ __launch_bounds__(256) void k_transp(
    const void* __restrict__ W, u16* __restrict__ WT, const int* __restrict__ flag,
    int Kd, int Nd)
{
    const int fd = flag[0];
    __shared__ u16 t[32][33];
    const int tx = threadIdx.x & 31, ty = threadIdx.x >> 5;   // 32 x 8
    #pragma unroll
    for (int r = 0; r < 32; r += 8) {
        int k = blockIdx.y * 32 + ty + r, n = blockIdx.x * 32 + tx;
        t[ty + r][tx] = f2bu(ldDyn(W, (size_t)k * Nd + n, fd));
    }
    __syncthreads();
    #pragma unroll
    for (int r = 0; r < 32; r += 8) {
        int n = blockIdx.x * 32 + ty + r, k = blockIdx.y * 32 + tx;
        WT[(size_t)n * Kd + k] = t[tx][ty + r];
    }
}

// ---------------------------------------------------------------------------
// MFMA bf16 GEMM: C[M,N] = op(A[M,K] @ B[K,N] + bias), B given as BT[N][K].
// 128x128 tile, BK=32, 4 waves x (4x4) 16x16x32 fragments.
// mode 0: C = acc+bias ; 1: C = gelu(acc+bias) ; 2: C(f32) += acc
// M%128==0, N%128==0, K%32==0; lda/ldbt in elements.
// ---------------------------------------------------------------------------
__global__ __launch_bounds__(256) void gemm_mfma(
    const u16* __restrict__ A, const u16* __restrict__ BT, const void* __restrict__ bias,
    void* __restrict__ Cc, const int* __restrict__ flag,
    int M, int N, int K, int lda, int ldbt, int ldc, size_t bOff, int mode, int outBf)
{
    const int fd = flag[0];
    __shared__ u16 As[128][56];   // stride 112 B: 16B-aligned frags, 2-way banks only
    __shared__ u16 Bs[128][56];
    const int m0 = blockIdx.y * 128;
    const int n0 = blockIdx.x * 128;
    const int tid = threadIdx.x;
    const int wave = tid >> 6, lane = tid & 63;
    const int q = lane >> 4, l16 = lane & 15;
    const int wm = (wave >> 1) * 64, wn = (wave & 1) * 64;

    f32x4 acc[4][4];
    #pragma unroll
    for (int i = 0; i < 4; ++i)
        #pragma unroll
        for (int j = 0; j < 4; ++j) acc[i][j] = (f32x4){0.f, 0.f, 0.f, 0.f};

    const int sr = tid >> 2;           // 0..63
    const int sc = (tid & 3) * 8;      // 0,8,16,24

    for (int k0 = 0; k0 < K; k0 += 32) {
        #pragma unroll
        for (int rr = 0; rr < 2; ++rr) {
            const u16* srcA = A + (size_t)(m0 + sr + rr * 64) * lda + k0 + sc;
            *(uint4*)&As[sr + rr * 64][sc] = *(const uint4*)srcA;
            const u16* srcB = BT + (size_t)(n0 + sr + rr * 64) * ldbt + k0 + sc;
            *(uint4*)&Bs[sr + rr * 64][sc] = *(const uint4*)srcB;
        }
        __syncthreads();
        bf16x8 af[4], bfr[4];
        #pragma unroll
        for (int i = 0; i < 4; ++i)
            af[i] = *(const bf16x8*)&As[wm + i * 16 + l16][q * 8];
        #pragma unroll
        for (int j = 0; j < 4; ++j)
            bfr[j] = *(const bf16x8*)&Bs[wn + j * 16 + l16][q * 8];
        #pragma unroll
        for (int i = 0; i < 4; ++i)
            #pragma unroll
            for (int j = 0; j < 4; ++j)
                acc[i][j] = __builtin_amdgcn_mfma_f32_16x16x32_bf16(af[i], bfr[j], acc[i][j], 0, 0, 0);
        __syncthreads();
    }

    #pragma unroll
    for (int i = 0; i < 4; ++i) {
        int row = m0 + wm + i * 16 + q * 4;
        #pragma unroll
        for (int j = 0; j < 4; ++j) {
            int col = n0 + wn + j * 16 + l16;
            #pragma unroll
            for (int r = 0; r < 4; ++r) {
                float v = acc[i][j][r];
                size_t idx = (size_t)(row + r) * ldc + col;
                if (mode == 2) {
                    ((float*)Cc)[idx] += v;
                } else {
                    v += ldDyn(bias, bOff + col, fd);
                    if (mode == 1) v = 0.5f * v * (1.0f + erff(v * 0.70710678118654752f));
                    if (outBf) ((u16*)Cc)[idx] = f2bu(v);
                    else       ((float*)Cc)[idx] = v;
                }
            }
        }
    }
}

// ---------------------------------------------------------------------------
// Naive tiled GEMM (small shapes): C[M,N] = A[M,K] @ W[K,N] + bias
// aKind: 0=bf16, 1=f32, 2=dynamic. W/bias dynamic.
// perm=1: write C at ((m>>6)<<15) + (n<<6) + (m&63)  (kbT layout), f32 out.
// ---------------------------------------------------------------------------
__global__ __launch_bounds__(256) void gemm_k(
    const void* __restrict__ A, const void* __restrict__ W, const void* __restrict__ bias,
    void* __restrict__ Cc, const int* __restrict__ flag,
    int M, int N, int K, int lda, int ldw, int ldc, int aKind, int perm)
{
    const int fd = flag[0];
    const int fA = (aKind == 2) ? fd : aKind;
    __shared__ float As[16][65];
    __shared__ float Bs[16][64];
    const int n0 = blockIdx.x * 64;
    const int m0 = blockIdx.y * 64;
    const int tid = threadIdx.x;
    const int tx = tid & 15, ty = tid >> 4;
    float acc[4][4] = {};

    for (int k0 = 0; k0 < K; k0 += 16) {
        {
            int e = tid * 4, m = e >> 4, kk = e & 15;
            float t4[4]; ld4Dyn(A, (size_t)(m0 + m) * lda + k0 + kk, fA, t4);
            As[kk+0][m] = t4[0]; As[kk+1][m] = t4[1]; As[kk+2][m] = t4[2]; As[kk+3][m] = t4[3];
        }
        {
            int e = tid * 4, kk = e >> 6, n = e & 63;
            float t4[4]; ld4Dyn(W, (size_t)(k0 + kk) * ldw + n0 + n, fd, t4);
            Bs[kk][n+0] = t4[0]; Bs[kk][n+1] = t4[1]; Bs[kk][n+2] = t4[2]; Bs[kk][n+3] = t4[3];
        }
        __syncthreads();
        #pragma unroll
        for (int kk = 0; kk < 16; ++kk) {
            float a[4], b[4];
            #pragma unroll
            for (int i = 0; i < 4; ++i) a[i] = As[kk][ty*4 + i];
            #pragma unroll
            for (int j = 0; j < 4; ++j) b[j] = Bs[kk][tx*4 + j];
            #pragma unroll
            for (int i = 0; i < 4; ++i)
                #pragma unroll
                for (int j = 0; j < 4; ++j) acc[i][j] += a[i] * b[j];
        }
        __syncthreads();
    }

    #pragma unroll
    for (int i = 0; i < 4; ++i) {
        int m = m0 + ty*4 + i;
        #pragma unroll
        for (int j = 0; j < 4; ++j) {
            int n = n0 + tx*4 + j;
            float v = acc[i][j] + ldDyn(bias, n, fd);
            size_t idx = perm ? (size_t)((m >> 6) << 15) + (n << 6) + (m & 63)
                              : (size_t)m * ldc + n;
            ((float*)Cc)[idx] = v;
        }
    }
}

// ---------------------------------------------------------------------------
// Softmax over L (axis=1) per (b,p) + inclusive prefix scan -> cumT (B,L+1,P)
// ---------------------------------------------------------------------------
__global__ __launch_bounds__(256) void k_softscan(
    const float* __restrict__ psc, const int* __restrict__ maskPAD,
    float* __restrict__ pAlpha, float* __restrict__ cumT)
{
    const int b = blockIdx.x >> 6;
    const int p = blockIdx.x & 63;
    const int tid = threadIdx.x;
    __shared__ float s0[1024], s1[1024];
    __shared__ float redA[4], redB[4];

    float acc[4];
    #pragma unroll
    for (int r = 0; r < 4; ++r) {
        int m = tid + r * 256;
        float a = psc[((size_t)b * LSEQ + m) * PDIM + p];
        if (maskPAD[(size_t)b * LSEQ * LSEQ + m] == 0) a = -32768.0f;
        acc[r] = a;
    }
    float mx = fmaxf(fmaxf(acc[0], acc[1]), fmaxf(acc[2], acc[3]));
    mx = wmax(mx);
    if ((tid & 63) == 0) redA[tid >> 6] = mx;
    __syncthreads();
    mx = fmaxf(fmaxf(redA[0], redA[1]), fmaxf(redA[2], redA[3]));

    float e[4], ls = 0.f;
    #pragma unroll
    for (int r = 0; r < 4; ++r) { e[r] = expf(acc[r] - mx); ls += e[r]; }
    ls = wsum(ls);
    if ((tid & 63) == 0) redB[tid >> 6] = ls;
    __syncthreads();
    float inv = 1.0f / (redB[0] + redB[1] + redB[2] + redB[3]);

    #pragma unroll
    for (int r = 0; r < 4; ++r) {
        int m = tid + r * 256;
        float pa = e[r] * inv;
        pAlpha[((size_t)b * LSEQ + m) * PDIM + p] = pa;
        s0[m] = pa;
    }
    __syncthreads();

    float* src = s0; float* dst = s1;
    for (int off = 1; off < 1024; off <<= 1) {
        #pragma unroll
        for (int r = 0; r < 4; ++r) {
            int i = tid + r * 256;
            float v = src[i];
            if (i >= off) v += src[i - off];
            dst[i] = v;
        }
        __syncthreads();
        float* t = src; src = dst; dst = t;
    }
    size_t cb = (size_t)b * (LSEQ + 1) * PDIM + p;
    if (tid == 0) cumT[cb] = 0.f;
    #pragma unroll
    for (int r = 0; r < 4; ++r) {
        int i = tid + r * 256;
        cumT[cb + (size_t)(i + 1) * PDIM] = src[i];
    }
}

// ---------------------------------------------------------------------------
// kxp[b,p,c] = sum_m pAlpha[b,m,p] * kx[b,m,c]  (and vxp from vx)
// ---------------------------------------------------------------------------
__global__ __launch_bounds__(512) void k_pool(
    const void* __restrict__ kx, const void* __restrict__ vx,
    const float* __restrict__ pAlpha, float* __restrict__ kxp, float* __restrict__ vxp,
    const int* __restrict__ flag)
{
    const int fd = flag[0];
    const int b  = blockIdx.x >> 4;
    const int p0 = (blockIdx.x & 15) * 4;
    const int c  = threadIdx.x;
    float aK[4] = {0,0,0,0}, aV[4] = {0,0,0,0};
    for (int m = 0; m < LSEQ; ++m) {
        size_t idx = ((size_t)b * LSEQ + m) * CDIM + c;
        float kv = ldDyn(kx, idx, fd);
        float vv = ldDyn(vx, idx, fd);
        const float* pa = pAlpha + ((size_t)b * LSEQ + m) * PDIM + p0;
        #pragma unroll
        for (int j = 0; j < 4; ++j) { float a = pa[j]; aK[j] += a * kv; aV[j] += a * vv; }
    }
    #pragma unroll
    for (int j = 0; j < 4; ++j) {
        kxp[((size_t)b * PDIM + p0 + j) * CDIM + c] = aK[j];
        vxp[((size_t)b * PDIM + p0 + j) * CDIM + c] = aV[j];
    }
}

// ---------------------------------------------------------------------------
// Attention: one block per (b,l), 512 threads. All global reads coalesced:
// cumT (B,L+1,P) lane=p; kbT (B, H*DK, P) lane=p; vb (B,P,H*DK) lane=h*64+d.
// q read from qz (bf16), z written back in place.
// ---------------------------------------------------------------------------
__global__ __launch_bounds__(512) void k_attn(
    u16* __restrict__ qz, const float* __restrict__ kbT, const float* __restrict__ vb,
    const float* __restrict__ cumT, const void* __restrict__ embK, const void* __restrict__ embB,
    const int* __restrict__ flag)
{
    const int fd = flag[0];
    const int b = blockIdx.x >> 10;
    const int l = blockIdx.x & 1023;
    const int tid = threadIdx.x;
    __shared__ float qrow[CDIM];
    __shared__ float S[15][PDIM];
    __shared__ float al[HH][PDIM];
    __shared__ float eK[15 * HH], eB[15 * HH];

    const size_t rowOff = ((size_t)b * LSEQ + l) * CDIM;
    qrow[tid] = b2f(qz[rowOff + tid]);
    if (tid < 15 * HH) { eK[tid] = ldDyn(embK, tid, fd); eB[tid] = ldDyn(embB, tid, fd); }

    const float* cb = cumT + (size_t)b * (LSEQ + 1) * PDIM;
    for (int idx = tid; idx < 15 * PDIM; idx += 512) {
        int t = idx >> 6, p = idx & 63;
        float s;
        if (t == 0) {
            s = cb[(size_t)(l + 1) * PDIM + p] - cb[(size_t)l * PDIM + p];
        } else {
            s = 0.f;
            int hi = l - c_dlo[t];
            int lo = l - c_dhi[t]; if (lo < 0) lo = 0;
            if (hi >= lo) s += cb[(size_t)(hi + 1) * PDIM + p] - cb[(size_t)lo * PDIM + p];
            lo = l + c_dlo[t];
            hi = l + c_dhi[t]; if (hi > LSEQ - 1) hi = LSEQ - 1;
            if (lo <= hi) s += cb[(size_t)(hi + 1) * PDIM + p] - cb[(size_t)lo * PDIM + p];
        }
        S[t][p] = s;
    }
    __syncthreads();

    const int h = tid >> 6, p = tid & 63;   // wave h, lane p
    const float* kcol = kbT + (size_t)b * CDIM * PDIM + (size_t)h * DKK * PDIM + p;
    const float* qh = qrow + h * DKK;
    float raw = 0.f;
    #pragma unroll 8
    for (int d = 0; d < DKK; ++d) raw += qh[d] * kcol[(size_t)d * PDIM];

    float kbm = 0.f, bbm = 0.f;
    #pragma unroll
    for (int t = 0; t < 15; ++t) {
        float sv = S[t][p];
        kbm += eK[t * HH + h] * sv;
        bbm += eB[t * HH + h] * sv;
    }
    float sc = raw * 0.125f * kbm + bbm;

    float mx = wmax(sc);
    float e = expf(sc - mx);
    float ssum = wsum(e);
    al[h][p] = e / ssum;
    __syncthreads();

    float z = 0.f;
    const float* vcol = vb + (size_t)b * PDIM * CDIM + tid;
    #pragma unroll 8
    for (int pp = 0; pp < PDIM; ++pp) z += al[h][pp] * vcol[(size_t)pp * CDIM];
    qz[rowOff + tid] = f2bu(z);
}

// ---------------------------------------------------------------------------
// LayerNorm: y = LN(a (+ badd)) * g + be ; optional out2 = y + bias2 (f32)
// aKind/outKind: 0=bf16, 1=f32, 2=dynamic
// ---------------------------------------------------------------------------
__global__ __launch_bounds__(512) void k_ln(
    const void* __restrict__ a, const u16* __restrict__ badd,
    const void* __restrict__ g, const void* __restrict__ be, const int* __restrict__ flag,
    void* __restrict__ out, float* __restrict__ out2, const void* __restrict__ bias2,
    int aKind, int outKind)
{
    const int fd = flag[0];
    const int fA = (aKind == 2) ? fd : aKind;
    const int fO = (outKind == 2) ? fd : outKind;
    const size_t row = blockIdx.x;
    const int c = threadIdx.x;
    float x = ldDyn(a, row * CDIM + c, fA);
    if (badd) x += b2f(badd[row * CDIM + c]);

    __shared__ float rA[8], rB[8];
    float s = wsum(x);
    if ((c & 63) == 0) rA[c >> 6] = s;
    __syncthreads();
    float tot = 0.f;
    #pragma unroll
    for (int w = 0; w < 8; ++w) tot += rA[w];
    float mu = tot * (1.0f / 512.0f);
    float dv = x - mu;
    float s2 = wsum(dv * dv);
    if ((c & 63) == 0) rB[c >> 6] = s2;
    __syncthreads();
    float v2 = 0.f;
    #pragma unroll
    for (int w = 0; w < 8; ++w) v2 += rB[w];
    float y = dv * rsqrtf(v2 * (1.0f / 512.0f) + 1e-5f) * ldDyn(g, c, fd) + ldDyn(be, c, fd);
    if (fO) ((float*)out)[row * CDIM + c] = y;
    else    ((u16*)out)[row * CDIM + c] = f2bu(y);
    if (out2) out2[row * CDIM + c] = y + ldDyn(bias2, c, fd);
}

// ---------------------------------------------------------------------------
extern "C" void kernel_launch(void* const* d_in, const int* in_sizes, int n_in,
                              void* d_out, int out_size, void* d_ws, size_t ws_size,
                              hipStream_t stream)
{
    (void)in_sizes; (void)n_in; (void)out_size; (void)ws_size;
    const void* qx   = d_in[0];
    const void* kx   = d_in[1];
    const void* vx   = d_in[2];
    const int*  mask = (const int*)d_in[3];
    const void* Wp   = d_in[4];
    const void* bp   = d_in[5];
    const void* WQ   = d_in[6];
    const void* bQ   = d_in[7];
    const void* WK   = d_in[8];
    const void* bK   = d_in[9];
    const void* WV   = d_in[10];
    const void* bV   = d_in[11];
    const void* WO   = d_in[12];
    const void* bO   = d_in[13];
    const void* embK = d_in[14];
    const void* embB = d_in[15];
    const void* l1g  = d_in[16];
    const void* l1b  = d_in[17];
    const void* l2g  = d_in[18];
    const void* l2b  = d_in[19];
    const void* W1   = d_in[20];
    const void* b1   = d_in[21];
    const void* W2   = d_in[22];
    const void* b2   = d_in[23];

    // workspace map (f32-element offsets); total ~105.9 MB
    float* ws     = (float*)d_ws;
    int*   flag   = (int*)d_ws;
    float* pAlpha = ws + 64;                       // 1,048,576
    float* cumT   = ws + 1048640;                  // 1,049,600 (B, L+1, P)
    float* kxp    = ws + 2098240;                  //   524,288
    float* vxp    = ws + 2622528;                  //   524,288
    float* kbT    = ws + 3146816;                  //   524,288 (B, H*DK, P)
    float* vb     = ws + 3671104;                  //   524,288 (B, P, H*DK)
    float* pre2   = ws + 4195392;                  // 8,388,608
    u16*   qz     = (u16*)(ws + 12584000);         // bf16 8.4M (q -> z -> z1)
    u16*   qxb    = (u16*)(ws + 16778304);         // bf16 8.4M (qx, later zo)
    u16*   zo     = qxb;                           // alias: qxb dead after q-proj
    u16*   hch    = (u16*)(ws + 20972608);         // bf16 8.4M (FFN hidden chunk)
    u16*   WqT    = (u16*)(ws + 25166912);         // bf16 262,144
    u16*   WoT    = (u16*)(ws + 25297984);         // bf16 262,144
    u16*   W1T    = (u16*)(ws + 25429056);         // bf16 1,048,576 [2048][512]
    u16*   W2T    = (u16*)(ws + 25953344);         // bf16 1,048,576 [512][2048]

    const int MROW = BI * LSEQ;                    // 16384

    // 0) dtype detection -> flag
    k_detect<<<dim3(1), dim3(256), 0, stream>>>((const unsigned int*)qx, flag);
    // 0b) qx -> bf16; weights -> bf16 transposed
    k_cvt<<<dim3(MROW * CDIM / 1024), dim3(256), 0, stream>>>(qx, qxb, flag, MROW * CDIM);
    k_transp<<<dim3(16, 16), dim3(256), 0, stream>>>(WQ, WqT, flag, 512, 512);
    k_transp<<<dim3(16, 16), dim3(256), 0, stream>>>(WO, WoT, flag, 512, 512);
    k_transp<<<dim3(64, 16), dim3(256), 0, stream>>>(W1, W1T, flag, 512, 2048);
    k_transp<<<dim3(16, 64), dim3(256), 0, stream>>>(W2, W2T, flag, 2048, 512);

    // 1) pScore = vx @ Wp + bp -> pAlpha region (f32)
    gemm_k<<<dim3(1, MROW / 64), dim3(256), 0, stream>>>(
        vx, Wp, bp, pAlpha, flag, MROW, PDIM, CDIM, CDIM, PDIM, PDIM, 2, 0);
    // 2) softmax over L + prefix scan -> pAlpha (in place), cumT
    k_softscan<<<dim3(BI * PDIM), dim3(256), 0, stream>>>(pAlpha, mask, pAlpha, cumT);
    // 3) pooling -> kxp, vxp
    k_pool<<<dim3(BI * 16), dim3(512), 0, stream>>>(kx, vx, pAlpha, kxp, vxp, flag);
    // 4) projections: q (MFMA -> qz bf16), k (naive, permuted -> kbT), v (naive -> vb)
    gemm_mfma<<<dim3(4, MROW / 128), dim3(256), 0, stream>>>(
        qxb, WqT, bQ, qz, flag, MROW, CDIM, CDIM, CDIM, CDIM, CDIM, 0, 0, 1);
    gemm_k<<<dim3(8, 16), dim3(256), 0, stream>>>(
        kxp, WK, bK, kbT, flag, BI * PDIM, CDIM, CDIM, CDIM, CDIM, CDIM, 1, 1);
    gemm_k<<<dim3(8, 16), dim3(256), 0, stream>>>(
        vxp, WV, bV, vb, flag, BI * PDIM, CDIM, CDIM, CDIM, CDIM, CDIM, 1, 0);
    // 5) attention: z overwrites q in qz
    k_attn<<<dim3(BI * LSEQ), dim3(512), 0, stream>>>(qz, kbT, vb, cumT, embK, embB, flag);
    // 6) zo = z @ WO + bO (bf16, into qxb alias)
    gemm_mfma<<<dim3(4, MROW / 128), dim3(256), 0, stream>>>(
        qz, WoT, bO, zo, flag, MROW, CDIM, CDIM, CDIM, CDIM, CDIM, 0, 0, 1);
    // 7) LN1: z1 = LN(vx + zo) -> qz (bf16) ; pre2 = z1 + b2 (f32)
    k_ln<<<dim3(MROW), dim3(512), 0, stream>>>(
        vx, zo, l1g, l1b, flag, qz, pre2, b2, 2, 0);
    // 8) FFN in 4 hidden chunks of 512:
    //    hch = gelu(z1 @ W1[:,jc] + b1[jc]) ; pre2 += hch @ W2[jc,:]
    for (int j = 0; j < 4; ++j) {
        gemm_mfma<<<dim3(4, MROW / 128), dim3(256), 0, stream>>>(
            qz, W1T + (size_t)j * 512 * 512, b1, hch, flag,
            MROW, 512, CDIM, CDIM, CDIM, 512, (size_t)j * 512, 1, 1);
        gemm_mfma<<<dim3(4, MROW / 128), dim3(256), 0, stream>>>(
            hch, W2T + (size_t)j * 512, nullptr, pre2, flag,
            MROW, CDIM, 512, 512, 2048, CDIM, 0, 2, 0);
    }
    // 9) LN2 -> d_out (dtype follows detection)
    k_ln<<<dim3(MROW), dim3(512), 0, stream>>>(
        pre2, nullptr, l2g, l2b, flag, d_out, nullptr, nullptr, 1, 2);
}

// Round 4
// 1035.178 us; speedup vs baseline: 2.2577x; 1.1813x over previous
//
#include <hip/hip_runtime.h>
#include <hip/hip_bf16.h>

// Shapes (fixed): B=16, L=1024, C=512, P=64, H=8, DK=64, MRD=7
#define BI   16
#define LSEQ 1024
#define CDIM 512
#define PDIM 64
#define HH   8
#define DKK  64

typedef __hip_bfloat16 bf16;
typedef unsigned short u16;
typedef __attribute__((ext_vector_type(8))) short bf16x8;
typedef __attribute__((ext_vector_type(4))) float f32x4;

// rel-pos bucket boundaries: bucket t covers |l-m| in [dlo[t], dhi[t]]
__constant__ int c_dlo[15] = {0,1,2,3,4,5,6,7, 9,11,15,23,39, 71,135};
__constant__ int c_dhi[15] = {0,1,2,3,4,5,6,8,10,14,22,38,70,134,1023};

__device__ __forceinline__ float b2f(u16 u) {
    union { unsigned int i; float f; } c; c.i = ((unsigned int)u) << 16; return c.f;
}
__device__ __forceinline__ u16 f2bu(float v) {
    bf16 h = __float2bfloat16(v);
    return *(u16*)&h;
}
// dynamic-dtype loads: f=1 -> fp32, f=0 -> bf16
__device__ __forceinline__ float ldDyn(const void* p, size_t i, int f) {
    return f ? ((const float*)p)[i] : b2f(((const u16*)p)[i]);
}
__device__ __forceinline__ void ld4Dyn(const void* p, size_t i, int f, float* o) {
    if (f) { float4 v = *(const float4*)((const float*)p + i);
             o[0]=v.x; o[1]=v.y; o[2]=v.z; o[3]=v.w; }
    else   { ushort4 u = *(const ushort4*)((const u16*)p + i);
             o[0]=b2f(u.x); o[1]=b2f(u.y); o[2]=b2f(u.z); o[3]=b2f(u.w); }
}

// async global->LDS, 16B per lane; lds base must be wave-uniform (HW writes
// base + lane*16). [measured: learn_hip m97]
__device__ __forceinline__ void gll16(const u16* g, u16* l) {
    __builtin_amdgcn_global_load_lds(
        (const __attribute__((address_space(1))) unsigned int*)g,
        (__attribute__((address_space(3))) unsigned int*)l,
        16, 0, 0);
}

__device__ __forceinline__ float wsum(float v) {
    #pragma unroll
    for (int o = 32; o; o >>= 1) v += __shfl_xor(v, o, 64);
    return v;
}
__device__ __forceinline__ float wmax(float v) {
    #pragma unroll
    for (int o = 32; o; o >>= 1) v = fmaxf(v, __shfl_xor(v, o, 64));
    return v;
}

// ---------------------------------------------------------------------------
// dtype detect: flag 0 = bf16, 1 = fp32
// ---------------------------------------------------------------------------
__global__ void k_detect(const unsigned int* __restrict__ qw, int* __restrict__ flag) {
    __shared__ int cnt;
    if (threadIdx.x == 0) cnt = 0;
    __syncthreads();
    int local = 0;
    for (int i = threadIdx.x; i < 4096; i += 256) {
        float fv = b2f((u16)(qw[i] & 0xFFFFu));
        float af = fabsf(fv);
        if (fv == 0.0f || (af >= 0.0009765625f && af <= 32.0f)) local++;
    }
    atomicAdd(&cnt, local);
    __syncthreads();
    if (threadIdx.x == 0) flag[0] = (cnt >= 2048) ? 0 : 1;
}

// ---------------------------------------------------------------------------
// convert dyn -> bf16 flat (n multiple of 4)
// ---------------------------------------------------------------------------
__global__ __launch_bounds__(256) void k_cvt(
    const void* __restrict__ src, u16* __restrict__ dst, const int* __restrict__ flag, int n)
{
    const int fd = flag[0];
    int i = (blockIdx.x * 256 + threadIdx.x) * 4;
    if (i >= n) return;
    float t[4]; ld4Dyn(src, i, fd, t);
    ushort4 o; o.x = f2bu(t[0]); o.y = f2bu(t[1]); o.z = f2bu(t[2]); o.w = f2bu(t[3]);
    *(ushort4*)(dst + i) = o;
}

// ---------------------------------------------------------------------------
// transpose dyn W[Kd][Nd] -> bf16 WT[Nd][Kd]; Kd,Nd multiples of 32
// ---------------------------------------------------------------------------
__global__ __launch_bounds__(256) void k_transp(
    const void* __restrict__ W, u16* __restrict__ WT, const int* __restrict__ flag,
    int Kd, int Nd)
{
    const int fd = flag[0];
    __shared__ u16 t[32][33];
    const int tx = threadIdx.x & 31, ty = threadIdx.x >> 5;   // 32 x 8
    #pragma unroll
    for (int r = 0; r < 32; r += 8) {
        int k = blockIdx.y * 32 + ty + r, n = blockIdx.x * 32 + tx;
        t[ty + r][tx] = f2bu(ldDyn(W, (size_t)k * Nd + n, fd));
    }
    __syncthreads();
    #pragma unroll
    for (int r = 0; r < 32; r += 8) {
        int n = blockIdx.x * 32 + ty + r, k = blockIdx.y * 32 + tx;
        WT[(size_t)n * Kd + k] = t[tx][ty + r];
    }
}

// ---------------------------------------------------------------------------
// MFMA bf16 GEMM: C[M,N] = op(A[M,K] @ B[K,N] + bias), B given as BT[N][K].
// 128x128 tile, BK=32, 4 waves x (4x4) 16x16x32 fragments.
// Staging via global_load_lds width=16 into UNPADDED [128][32] LDS tiles
// (row stride 64 B == the DMA's lane*16 pattern; padding would break it).
// mode 0: C = acc+bias ; 1: C = gelu(acc+bias) ; 2: C(f32) += acc
// ---------------------------------------------------------------------------
__global__ __launch_bounds__(256) void gemm_mfma(
    const u16* __restrict__ A, const u16* __restrict__ BT, const void* __restrict__ bias,
    void* __restrict__ Cc, const int* __restrict__ flag,
    int M, int N, int K, int lda, int ldbt, int ldc, size_t bOff, int mode, int outBf)
{
    const int fd = flag[0];
    __shared__ u16 As[128][32];
    __shared__ u16 Bs[128][32];
    const int m0 = blockIdx.y * 128;
    const int n0 = blockIdx.x * 128;
    const int tid = threadIdx.x;
    const int wave = tid >> 6, lane = tid & 63;
    const int q = lane >> 4, l16 = lane & 15;
    const int wm = (wave >> 1) * 64, wn = (wave & 1) * 64;

    f32x4 acc[4][4];
    #pragma unroll
    for (int i = 0; i < 4; ++i)
        #pragma unroll
        for (int j = 0; j < 4; ++j) acc[i][j] = (f32x4){0.f, 0.f, 0.f, 0.f};

    const int srow = wave * 16 + (lane >> 2);  // row within 64-row pass
    const int scol = (lane & 3) * 8;           // element col (16B per lane)

    for (int k0 = 0; k0 < K; k0 += 32) {
        #pragma unroll
        for (int pass = 0; pass < 2; ++pass) {
            int row = pass * 64 + srow;
            gll16(A + (size_t)(m0 + row) * lda + k0 + scol,
                  &As[pass * 64 + wave * 16][0]);
            gll16(BT + (size_t)(n0 + row) * ldbt + k0 + scol,
                  &Bs[pass * 64 + wave * 16][0]);
        }
        __syncthreads();
        bf16x8 af[4], bfr[4];
        #pragma unroll
        for (int i = 0; i < 4; ++i)
            af[i] = *(const bf16x8*)&As[wm + i * 16 + l16][q * 8];
        #pragma unroll
        for (int j = 0; j < 4; ++j)
            bfr[j] = *(const bf16x8*)&Bs[wn + j * 16 + l16][q * 8];
        #pragma unroll
        for (int i = 0; i < 4; ++i)
            #pragma unroll
            for (int j = 0; j < 4; ++j)
                acc[i][j] = __builtin_amdgcn_mfma_f32_16x16x32_bf16(af[i], bfr[j], acc[i][j], 0, 0, 0);
        __syncthreads();
    }

    #pragma unroll
    for (int i = 0; i < 4; ++i) {
        int row = m0 + wm + i * 16 + q * 4;
        #pragma unroll
        for (int j = 0; j < 4; ++j) {
            int col = n0 + wn + j * 16 + l16;
            #pragma unroll
            for (int r = 0; r < 4; ++r) {
                float v = acc[i][j][r];
                size_t idx = (size_t)(row + r) * ldc + col;
                if (mode == 2) {
                    ((float*)Cc)[idx] += v;
                } else {
                    v += ldDyn(bias, bOff + col, fd);
                    if (mode == 1) v = 0.5f * v * (1.0f + erff(v * 0.70710678118654752f));
                    if (outBf) ((u16*)Cc)[idx] = f2bu(v);
                    else       ((float*)Cc)[idx] = v;
                }
            }
        }
    }
}

// ---------------------------------------------------------------------------
// Naive tiled GEMM (small shapes): C[M,N] = A[M,K] @ W[K,N] + bias
// perm=1: write C at ((m>>6)<<15) + (n<<6) + (m&63)  (kbT layout), f32 out.
// ---------------------------------------------------------------------------
__global__ __launch_bounds__(256) void gemm_k(
    const void* __restrict__ A, const void* __restrict__ W, const void* __restrict__ bias,
    void* __restrict__ Cc, const int* __restrict__ flag,
    int M, int N, int K, int lda, int ldw, int ldc, int aKind, int perm)
{
    const int fd = flag[0];
    const int fA = (aKind == 2) ? fd : aKind;
    __shared__ float As[16][65];
    __shared__ float Bs[16][64];
    const int n0 = blockIdx.x * 64;
    const int m0 = blockIdx.y * 64;
    const int tid = threadIdx.x;
    const int tx = tid & 15, ty = tid >> 4;
    float acc[4][4] = {};

    for (int k0 = 0; k0 < K; k0 += 16) {
        {
            int e = tid * 4, m = e >> 4, kk = e & 15;
            float t4[4]; ld4Dyn(A, (size_t)(m0 + m) * lda + k0 + kk, fA, t4);
            As[kk+0][m] = t4[0]; As[kk+1][m] = t4[1]; As[kk+2][m] = t4[2]; As[kk+3][m] = t4[3];
        }
        {
            int e = tid * 4, kk = e >> 6, n = e & 63;
            float t4[4]; ld4Dyn(W, (size_t)(k0 + kk) * ldw + n0 + n, fd, t4);
            Bs[kk][n+0] = t4[0]; Bs[kk][n+1] = t4[1]; Bs[kk][n+2] = t4[2]; Bs[kk][n+3] = t4[3];
        }
        __syncthreads();
        #pragma unroll
        for (int kk = 0; kk < 16; ++kk) {
            float a[4], b[4];
            #pragma unroll
            for (int i = 0; i < 4; ++i) a[i] = As[kk][ty*4 + i];
            #pragma unroll
            for (int j = 0; j < 4; ++j) b[j] = Bs[kk][tx*4 + j];
            #pragma unroll
            for (int i = 0; i < 4; ++i)
                #pragma unroll
                for (int j = 0; j < 4; ++j) acc[i][j] += a[i] * b[j];
        }
        __syncthreads();
    }

    #pragma unroll
    for (int i = 0; i < 4; ++i) {
        int m = m0 + ty*4 + i;
        #pragma unroll
        for (int j = 0; j < 4; ++j) {
            int n = n0 + tx*4 + j;
            float v = acc[i][j] + ldDyn(bias, n, fd);
            size_t idx = perm ? (size_t)((m >> 6) << 15) + (n << 6) + (m & 63)
                              : (size_t)m * ldc + n;
            ((float*)Cc)[idx] = v;
        }
    }
}

// ---------------------------------------------------------------------------
// Softmax over L (axis=1) per (b,p) + inclusive prefix scan -> cumT (B,L+1,P)
// ---------------------------------------------------------------------------
__global__ __launch_bounds__(256) void k_softscan(
    const float* __restrict__ psc, const int* __restrict__ maskPAD,
    float* __restrict__ pAlpha, float* __restrict__ cumT)
{
    const int b = blockIdx.x >> 6;
    const int p = blockIdx.x & 63;
    const int tid = threadIdx.x;
    __shared__ float s0[1024], s1[1024];
    __shared__ float redA[4], redB[4];

    float acc[4];
    #pragma unroll
    for (int r = 0; r < 4; ++r) {
        int m = tid + r * 256;
        float a = psc[((size_t)b * LSEQ + m) * PDIM + p];
        if (maskPAD[(size_t)b * LSEQ * LSEQ + m] == 0) a = -32768.0f;
        acc[r] = a;
    }
    float mx = fmaxf(fmaxf(acc[0], acc[1]), fmaxf(acc[2], acc[3]));
    mx = wmax(mx);
    if ((tid & 63) == 0) redA[tid >> 6] = mx;
    __syncthreads();
    mx = fmaxf(fmaxf(redA[0], redA[1]), fmaxf(redA[2], redA[3]));

    float e[4], ls = 0.f;
    #pragma unroll
    for (int r = 0; r < 4; ++r) { e[r] = expf(acc[r] - mx); ls += e[r]; }
    ls = wsum(ls);
    if ((tid & 63) == 0) redB[tid >> 6] = ls;
    __syncthreads();
    float inv = 1.0f / (redB[0] + redB[1] + redB[2] + redB[3]);

    #pragma unroll
    for (int r = 0; r < 4; ++r) {
        int m = tid + r * 256;
        float pa = e[r] * inv;
        pAlpha[((size_t)b * LSEQ + m) * PDIM + p] = pa;
        s0[m] = pa;
    }
    __syncthreads();

    float* src = s0; float* dst = s1;
    for (int off = 1; off < 1024; off <<= 1) {
        #pragma unroll
        for (int r = 0; r < 4; ++r) {
            int i = tid + r * 256;
            float v = src[i];
            if (i >= off) v += src[i - off];
            dst[i] = v;
        }
        __syncthreads();
        float* t = src; src = dst; dst = t;
    }
    size_t cb = (size_t)b * (LSEQ + 1) * PDIM + p;
    if (tid == 0) cumT[cb] = 0.f;
    #pragma unroll
    for (int r = 0; r < 4; ++r) {
        int i = tid + r * 256;
        cumT[cb + (size_t)(i + 1) * PDIM] = src[i];
    }
}

// ---------------------------------------------------------------------------
// Pooling, single-read: grid (b x 16 m-chunks), thread = channel c.
// kxp[b,p,c] += sum_{m in chunk} pAlpha[b,m,p]*kx[b,m,c]  via 64 VGPR accums
// per array and one coalesced atomicAdd pass. kx/vx fetched exactly once.
// ---------------------------------------------------------------------------
__global__ __launch_bounds__(512) void k_pool(
    const void* __restrict__ kx, const void* __restrict__ vx,
    const float* __restrict__ pAlpha, float* __restrict__ kxp, float* __restrict__ vxp,
    const int* __restrict__ flag)
{
    const int fd = flag[0];
    const int b  = blockIdx.x >> 4;
    const int m0 = (blockIdx.x & 15) * 64;
    const int c  = threadIdx.x;
    __shared__ float pach[64][64];

    for (int i = threadIdx.x; i < 64 * 16; i += 512) {
        int e = i * 4, m = e >> 6, p = e & 63;
        *(float4*)&pach[m][p] = *(const float4*)&pAlpha[((size_t)b * LSEQ + m0 + m) * PDIM + p];
    }
    __syncthreads();

    float aK[64] = {}, aV[64] = {};
    #pragma unroll 2
    for (int m = 0; m < 64; ++m) {
        size_t idx = ((size_t)b * LSEQ + m0 + m) * CDIM + c;
        float kv = ldDyn(kx, idx, fd);
        float vv = ldDyn(vx, idx, fd);
        #pragma unroll
        for (int p4 = 0; p4 < 16; ++p4) {
            float4 pa = *(const float4*)&pach[m][p4 * 4];
            aK[p4*4+0] += pa.x * kv;  aV[p4*4+0] += pa.x * vv;
            aK[p4*4+1] += pa.y * kv;  aV[p4*4+1] += pa.y * vv;
            aK[p4*4+2] += pa.z * kv;  aV[p4*4+2] += pa.z * vv;
            aK[p4*4+3] += pa.w * kv;  aV[p4*4+3] += pa.w * vv;
        }
    }
    #pragma unroll
    for (int p = 0; p < 64; ++p) {
        atomicAdd(&kxp[((size_t)b * PDIM + p) * CDIM + c], aK[p]);
        atomicAdd(&vxp[((size_t)b * PDIM + p) * CDIM + c], aV[p]);
    }
}

// ---------------------------------------------------------------------------
// Attention: one block per (b,l), 512 threads; all global reads coalesced.
// ---------------------------------------------------------------------------
__global__ __launch_bounds__(512) void k_attn(
    u16* __restrict__ qz, const float* __restrict__ kbT, const float* __restrict__ vb,
    const float* __restrict__ cumT, const void* __restrict__ embK, const void* __restrict__ embB,
    const int* __restrict__ flag)
{
    const int fd = flag[0];
    const int b = blockIdx.x >> 10;
    const int l = blockIdx.x & 1023;
    const int tid = threadIdx.x;
    __shared__ float qrow[CDIM];
    __shared__ float S[15][PDIM];
    __shared__ float al[HH][PDIM];
    __shared__ float eK[15 * HH], eB[15 * HH];

    const size_t rowOff = ((size_t)b * LSEQ + l) * CDIM;
    qrow[tid] = b2f(qz[rowOff + tid]);
    if (tid < 15 * HH) { eK[tid] = ldDyn(embK, tid, fd); eB[tid] = ldDyn(embB, tid, fd); }

    const float* cb = cumT + (size_t)b * (LSEQ + 1) * PDIM;
    for (int idx = tid; idx < 15 * PDIM; idx += 512) {
        int t = idx >> 6, p = idx & 63;
        float s;
        if (t == 0) {
            s = cb[(size_t)(l + 1) * PDIM + p] - cb[(size_t)l * PDIM + p];
        } else {
            s = 0.f;
            int hi = l - c_dlo[t];
            int lo = l - c_dhi[t]; if (lo < 0) lo = 0;
            if (hi >= lo) s += cb[(size_t)(hi + 1) * PDIM + p] - cb[(size_t)lo * PDIM + p];
            lo = l + c_dlo[t];
            hi = l + c_dhi[t]; if (hi > LSEQ - 1) hi = LSEQ - 1;
            if (lo <= hi) s += cb[(size_t)(hi + 1) * PDIM + p] - cb[(size_t)lo * PDIM + p];
        }
        S[t][p] = s;
    }
    __syncthreads();

    const int h = tid >> 6, p = tid & 63;   // wave h, lane p
    const float* kcol = kbT + (size_t)b * CDIM * PDIM + (size_t)h * DKK * PDIM + p;
    const float* qh = qrow + h * DKK;
    float raw = 0.f;
    #pragma unroll 8
    for (int d = 0; d < DKK; ++d) raw += qh[d] * kcol[(size_t)d * PDIM];

    float kbm = 0.f, bbm = 0.f;
    #pragma unroll
    for (int t = 0; t < 15; ++t) {
        float sv = S[t][p];
        kbm += eK[t * HH + h] * sv;
        bbm += eB[t * HH + h] * sv;
    }
    float sc = raw * 0.125f * kbm + bbm;

    float mx = wmax(sc);
    float e = expf(sc - mx);
    float ssum = wsum(e);
    al[h][p] = e / ssum;
    __syncthreads();

    float z = 0.f;
    const float* vcol = vb + (size_t)b * PDIM * CDIM + tid;
    #pragma unroll 8
    for (int pp = 0; pp < PDIM; ++pp) z += al[h][pp] * vcol[(size_t)pp * CDIM];
    qz[rowOff + tid] = f2bu(z);
}

// ---------------------------------------------------------------------------
// LayerNorm: y = LN(a (+ badd)) * g + be ; optional out2 = y + bias2 (f32)
// ---------------------------------------------------------------------------
__global__ __launch_bounds__(512) void k_ln(
    const void* __restrict__ a, const u16* __restrict__ badd,
    const void* __restrict__ g, const void* __restrict__ be, const int* __restrict__ flag,
    void* __restrict__ out, float* __restrict__ out2, const void* __restrict__ bias2,
    int aKind, int outKind)
{
    const int fd = flag[0];
    const int fA = (aKind == 2) ? fd : aKind;
    const int fO = (outKind == 2) ? fd : outKind;
    const size_t row = blockIdx.x;
    const int c = threadIdx.x;
    float x = ldDyn(a, row * CDIM + c, fA);
    if (badd) x += b2f(badd[row * CDIM + c]);

    __shared__ float rA[8], rB[8];
    float s = wsum(x);
    if ((c & 63) == 0) rA[c >> 6] = s;
    __syncthreads();
    float tot = 0.f;
    #pragma unroll
    for (int w = 0; w < 8; ++w) tot += rA[w];
    float mu = tot * (1.0f / 512.0f);
    float dv = x - mu;
    float s2 = wsum(dv * dv);
    if ((c & 63) == 0) rB[c >> 6] = s2;
    __syncthreads();
    float v2 = 0.f;
    #pragma unroll
    for (int w = 0; w < 8; ++w) v2 += rB[w];
    float y = dv * rsqrtf(v2 * (1.0f / 512.0f) + 1e-5f) * ldDyn(g, c, fd) + ldDyn(be, c, fd);
    if (fO) ((float*)out)[row * CDIM + c] = y;
    else    ((u16*)out)[row * CDIM + c] = f2bu(y);
    if (out2) out2[row * CDIM + c] = y + ldDyn(bias2, c, fd);
}

// ---------------------------------------------------------------------------
extern "C" void kernel_launch(void* const* d_in, const int* in_sizes, int n_in,
                              void* d_out, int out_size, void* d_ws, size_t ws_size,
                              hipStream_t stream)
{
    (void)in_sizes; (void)n_in; (void)out_size; (void)ws_size;
    const void* qx   = d_in[0];
    const void* kx   = d_in[1];
    const void* vx   = d_in[2];
    const int*  mask = (const int*)d_in[3];
    const void* Wp   = d_in[4];
    const void* bp   = d_in[5];
    const void* WQ   = d_in[6];
    const void* bQ   = d_in[7];
    const void* WK   = d_in[8];
    const void* bK   = d_in[9];
    const void* WV   = d_in[10];
    const void* bV   = d_in[11];
    const void* WO   = d_in[12];
    const void* bO   = d_in[13];
    const void* embK = d_in[14];
    const void* embB = d_in[15];
    const void* l1g  = d_in[16];
    const void* l1b  = d_in[17];
    const void* l2g  = d_in[18];
    const void* l2b  = d_in[19];
    const void* W1   = d_in[20];
    const void* b1   = d_in[21];
    const void* W2   = d_in[22];
    const void* b2   = d_in[23];

    // workspace map (f32-element offsets); total ~105.9 MB
    float* ws     = (float*)d_ws;
    int*   flag   = (int*)d_ws;
    float* pAlpha = ws + 64;                       // 1,048,576
    float* cumT   = ws + 1048640;                  // 1,049,600 (B, L+1, P)
    float* kxp    = ws + 2098240;                  //   524,288
    float* vxp    = ws + 2622528;                  //   524,288 (contiguous after kxp)
    float* kbT    = ws + 3146816;                  //   524,288 (B, H*DK, P)
    float* vb     = ws + 3671104;                  //   524,288 (B, P, H*DK)
    float* pre2   = ws + 4195392;                  // 8,388,608
    u16*   qz     = (u16*)(ws + 12584000);         // bf16 8.4M (q -> z -> z1)
    u16*   qxb    = (u16*)(ws + 16778304);         // bf16 8.4M (qx, later zo)
    u16*   zo     = qxb;                           // alias: qxb dead after q-proj
    u16*   hch    = (u16*)(ws + 20972608);         // bf16 8.4M (FFN hidden chunk)
    u16*   WqT    = (u16*)(ws + 25166912);         // bf16 262,144
    u16*   WoT    = (u16*)(ws + 25297984);         // bf16 262,144
    u16*   W1T    = (u16*)(ws + 25429056);         // bf16 1,048,576 [2048][512]
    u16*   W2T    = (u16*)(ws + 25953344);         // bf16 1,048,576 [512][2048]

    const int MROW = BI * LSEQ;                    // 16384

    // 0) dtype detection -> flag
    k_detect<<<dim3(1), dim3(256), 0, stream>>>((const unsigned int*)qx, flag);
    // 0b) qx -> bf16; weights -> bf16 transposed; zero the pooling accumulators
    k_cvt<<<dim3(MROW * CDIM / 1024), dim3(256), 0, stream>>>(qx, qxb, flag, MROW * CDIM);
    k_transp<<<dim3(16, 16), dim3(256), 0, stream>>>(WQ, WqT, flag, 512, 512);
    k_transp<<<dim3(16, 16), dim3(256), 0, stream>>>(WO, WoT, flag, 512, 512);
    k_transp<<<dim3(64, 16), dim3(256), 0, stream>>>(W1, W1T, flag, 512, 2048);
    k_transp<<<dim3(16, 64), dim3(256), 0, stream>>>(W2, W2T, flag, 2048, 512);
    hipMemsetAsync(kxp, 0, 2 * 524288 * sizeof(float), stream);   // kxp+vxp

    // 1) pScore = vx @ Wp + bp -> pAlpha region (f32)
    gemm_k<<<dim3(1, MROW / 64), dim3(256), 0, stream>>>(
        vx, Wp, bp, pAlpha, flag, MROW, PDIM, CDIM, CDIM, PDIM, PDIM, 2, 0);
    // 2) softmax over L + prefix scan -> pAlpha (in place), cumT
    k_softscan<<<dim3(BI * PDIM), dim3(256), 0, stream>>>(pAlpha, mask, pAlpha, cumT);
    // 3) pooling -> kxp, vxp (single-read, atomic accumulate)
    k_pool<<<dim3(BI * 16), dim3(512), 0, stream>>>(kx, vx, pAlpha, kxp, vxp, flag);
    // 4) projections: q (MFMA -> qz bf16), k (naive, permuted -> kbT), v (naive -> vb)
    gemm_mfma<<<dim3(4, MROW / 128), dim3(256), 0, stream>>>(
        qxb, WqT, bQ, qz, flag, MROW, CDIM, CDIM, CDIM, CDIM, CDIM, 0, 0, 1);
    gemm_k<<<dim3(8, 16), dim3(256), 0, stream>>>(
        kxp, WK, bK, kbT, flag, BI * PDIM, CDIM, CDIM, CDIM, CDIM, CDIM, 1, 1);
    gemm_k<<<dim3(8, 16), dim3(256), 0, stream>>>(
        vxp, WV, bV, vb, flag, BI * PDIM, CDIM, CDIM, CDIM, CDIM, CDIM, 1, 0);
    // 5) attention: z overwrites q in qz
    k_attn<<<dim3(BI * LSEQ), dim3(512), 0, stream>>>(qz, kbT, vb, cumT, embK, embB, flag);
    // 6) zo = z @ WO + bO (bf16, into qxb alias)
    gemm_mfma<<<dim3(4, MROW / 128), dim3(256), 0, stream>>>(
        qz, WoT, bO, zo, flag, MROW, CDIM, CDIM, CDIM, CDIM, CDIM, 0, 0, 1);
    // 7) LN1: z1 = LN(vx + zo) -> qz (bf16) ; pre2 = z1 + b2 (f32)
    k_ln<<<dim3(MROW), dim3(512), 0, stream>>>(
        vx, zo, l1g, l1b, flag, qz, pre2, b2, 2, 0);
    // 8) FFN in 4 hidden chunks of 512
    for (int j = 0; j < 4; ++j) {
        gemm_mfma<<<dim3(4, MROW / 128), dim3(256), 0, stream>>>(
            qz, W1T + (size_t)j * 512 * 512, b1, hch, flag,
            MROW, 512, CDIM, CDIM, CDIM, 512, (size_t)j * 512, 1, 1);
        gemm_mfma<<<dim3(4, MROW / 128), dim3(256), 0, stream>>>(
            hch, W2T + (size_t)j * 512, nullptr, pre2, flag,
            MROW, CDIM, 512, 512, 2048, CDIM, 0, 2, 0);
    }
    // 9) LN2 -> d_out (dtype follows detection)
    k_ln<<<dim3(MROW), dim3(512), 0, stream>>>(
        pre2, nullptr, l2g, l2b, flag, d_out, nullptr, nullptr, 1, 2);
}

// Round 5
// 1019.202 us; speedup vs baseline: 2.2931x; 1.0157x over previous
//
#include <hip/hip_runtime.h>
#include <hip/hip_bf16.h>

// Shapes (fixed): B=16, L=1024, C=512, P=64, H=8, DK=64, MRD=7
#define BI   16
#define LSEQ 1024
#define CDIM 512
#define PDIM 64
#define HH   8
#define DKK  64
#define LCH  32   // l's per attention block

typedef __hip_bfloat16 bf16;
typedef unsigned short u16;
typedef __attribute__((ext_vector_type(8))) short bf16x8;
typedef __attribute__((ext_vector_type(4))) float f32x4;

// rel-pos bucket boundaries: bucket t covers |l-m| in [dlo[t], dhi[t]]
__constant__ int c_dlo[15] = {0,1,2,3,4,5,6,7, 9,11,15,23,39, 71,135};
__constant__ int c_dhi[15] = {0,1,2,3,4,5,6,8,10,14,22,38,70,134,1023};

__device__ __forceinline__ float b2f(u16 u) {
    union { unsigned int i; float f; } c; c.i = ((unsigned int)u) << 16; return c.f;
}
__device__ __forceinline__ u16 f2bu(float v) {
    bf16 h = __float2bfloat16(v);
    return *(u16*)&h;
}
// dynamic-dtype loads: f=1 -> fp32, f=0 -> bf16
__device__ __forceinline__ float ldDyn(const void* p, size_t i, int f) {
    return f ? ((const float*)p)[i] : b2f(((const u16*)p)[i]);
}
__device__ __forceinline__ void ld4Dyn(const void* p, size_t i, int f, float* o) {
    if (f) { float4 v = *(const float4*)((const float*)p + i);
             o[0]=v.x; o[1]=v.y; o[2]=v.z; o[3]=v.w; }
    else   { ushort4 u = *(const ushort4*)((const u16*)p + i);
             o[0]=b2f(u.x); o[1]=b2f(u.y); o[2]=b2f(u.z); o[3]=b2f(u.w); }
}

// async global->LDS, 16B/lane; lds base wave-uniform (HW: base + lane*16)
__device__ __forceinline__ void gll16(const u16* g, u16* l) {
    __builtin_amdgcn_global_load_lds(
        (const __attribute__((address_space(1))) unsigned int*)g,
        (__attribute__((address_space(3))) unsigned int*)l,
        16, 0, 0);
}

__device__ __forceinline__ float wsum(float v) {
    #pragma unroll
    for (int o = 32; o; o >>= 1) v += __shfl_xor(v, o, 64);
    return v;
}
__device__ __forceinline__ float wmax(float v) {
    #pragma unroll
    for (int o = 32; o; o >>= 1) v = fmaxf(v, __shfl_xor(v, o, 64));
    return v;
}

// ---------------------------------------------------------------------------
// dtype detect: flag 0 = bf16, 1 = fp32
// ---------------------------------------------------------------------------
__global__ void k_detect(const unsigned int* __restrict__ qw, int* __restrict__ flag) {
    __shared__ int cnt;
    if (threadIdx.x == 0) cnt = 0;
    __syncthreads();
    int local = 0;
    for (int i = threadIdx.x; i < 4096; i += 256) {
        float fv = b2f((u16)(qw[i] & 0xFFFFu));
        float af = fabsf(fv);
        if (fv == 0.0f || (af >= 0.0009765625f && af <= 32.0f)) local++;
    }
    atomicAdd(&cnt, local);
    __syncthreads();
    if (threadIdx.x == 0) flag[0] = (cnt >= 2048) ? 0 : 1;
}

// ---------------------------------------------------------------------------
// convert -> bf16 flat (n multiple of 4); aKind: 0=bf16, 1=f32, 2=dynamic
// ---------------------------------------------------------------------------
__global__ __launch_bounds__(256) void k_cvt(
    const void* __restrict__ src, u16* __restrict__ dst, const int* __restrict__ flag,
    int n, int aKind)
{
    const int fA = (aKind == 2) ? flag[0] : aKind;
    int i = (blockIdx.x * 256 + threadIdx.x) * 4;
    if (i >= n) return;
    float t[4]; ld4Dyn(src, i, fA, t);
    ushort4 o; o.x = f2bu(t[0]); o.y = f2bu(t[1]); o.z = f2bu(t[2]); o.w = f2bu(t[3]);
    *(ushort4*)(dst + i) = o;
}

// ---------------------------------------------------------------------------
// transpose dyn W[Kd][Nd] -> bf16 WT[Nd][Kd]; Kd,Nd multiples of 32
// ---------------------------------------------------------------------------
__global__ __launch_bounds__(256) void k_transp(
    const void* __restrict__ W, u16* __restrict__ WT, const int* __restrict__ flag,
    int Kd, int Nd)
{
    const int fd = flag[0];
    __shared__ u16 t[32][33];
    const int tx = threadIdx.x & 31, ty = threadIdx.x >> 5;   // 32 x 8
    #pragma unroll
    for (int r = 0; r < 32; r += 8) {
        int k = blockIdx.y * 32 + ty + r, n = blockIdx.x * 32 + tx;
        t[ty + r][tx] = f2bu(ldDyn(W, (size_t)k * Nd + n, fd));
    }
    __syncthreads();
    #pragma unroll
    for (int r = 0; r < 32; r += 8) {
        int n = blockIdx.x * 32 + ty + r, k = blockIdx.y * 32 + tx;
        WT[(size_t)n * Kd + k] = t[tx][ty + r];
    }
}

// ---------------------------------------------------------------------------
// MFMA bf16 GEMM: C[M,N] = op(A[M,K] @ B[K,N] + bias), B given as BT[N][K].
// 128x128 tile, BK=32, 4 waves x (4x4) 16x16x32 fragments.
// global_load_lds width=16 into UNPADDED [128][32] tiles.
// mode 0: C = acc+bias ; 1: C = gelu(acc+bias) ; 2: C(f32) += acc
// perm=1 (mode 0, f32): write at ((m>>6)<<15)+(n<<6)+(m&63)  (kbT layout)
// ---------------------------------------------------------------------------
__global__ __launch_bounds__(256) void gemm_mfma(
    const u16* __restrict__ A, const u16* __restrict__ BT, const void* __restrict__ bias,
    void* __restrict__ Cc, const int* __restrict__ flag,
    int M, int N, int K, int lda, int ldbt, int ldc, size_t bOff, int mode, int outBf,
    int perm)
{
    const int fd = flag[0];
    __shared__ u16 As[128][32];
    __shared__ u16 Bs[128][32];
    const int m0 = blockIdx.y * 128;
    const int n0 = blockIdx.x * 128;
    const int tid = threadIdx.x;
    const int wave = tid >> 6, lane = tid & 63;
    const int q = lane >> 4, l16 = lane & 15;
    const int wm = (wave >> 1) * 64, wn = (wave & 1) * 64;

    f32x4 acc[4][4];
    #pragma unroll
    for (int i = 0; i < 4; ++i)
        #pragma unroll
        for (int j = 0; j < 4; ++j) acc[i][j] = (f32x4){0.f, 0.f, 0.f, 0.f};

    const int srow = wave * 16 + (lane >> 2);
    const int scol = (lane & 3) * 8;

    for (int k0 = 0; k0 < K; k0 += 32) {
        #pragma unroll
        for (int pass = 0; pass < 2; ++pass) {
            int row = pass * 64 + srow;
            gll16(A + (size_t)(m0 + row) * lda + k0 + scol, &As[pass * 64 + wave * 16][0]);
            gll16(BT + (size_t)(n0 + row) * ldbt + k0 + scol, &Bs[pass * 64 + wave * 16][0]);
        }
        __syncthreads();
        bf16x8 af[4], bfr[4];
        #pragma unroll
        for (int i = 0; i < 4; ++i) af[i] = *(const bf16x8*)&As[wm + i * 16 + l16][q * 8];
        #pragma unroll
        for (int j = 0; j < 4; ++j) bfr[j] = *(const bf16x8*)&Bs[wn + j * 16 + l16][q * 8];
        #pragma unroll
        for (int i = 0; i < 4; ++i)
            #pragma unroll
            for (int j = 0; j < 4; ++j)
                acc[i][j] = __builtin_amdgcn_mfma_f32_16x16x32_bf16(af[i], bfr[j], acc[i][j], 0, 0, 0);
        __syncthreads();
    }

    #pragma unroll
    for (int i = 0; i < 4; ++i) {
        int row = m0 + wm + i * 16 + q * 4;
        #pragma unroll
        for (int j = 0; j < 4; ++j) {
            int col = n0 + wn + j * 16 + l16;
            #pragma unroll
            for (int r = 0; r < 4; ++r) {
                float v = acc[i][j][r];
                int m = row + r;
                if (mode == 2) {
                    ((float*)Cc)[(size_t)m * ldc + col] += v;
                } else {
                    v += ldDyn(bias, bOff + col, fd);
                    if (mode == 1) v = 0.5f * v * (1.0f + erff(v * 0.70710678118654752f));
                    size_t idx = perm ? (size_t)((m >> 6) << 15) + ((size_t)col << 6) + (m & 63)
                                      : (size_t)m * ldc + col;
                    if (outBf) ((u16*)Cc)[idx] = f2bu(v);
                    else       ((float*)Cc)[idx] = v;
                }
            }
        }
    }
}

// ---------------------------------------------------------------------------
// MFMA bf16 GEMM, 128m x 64n tile (for N=64): 4 waves stacked in m.
// C = A @ BT^T + bias, f32 out, ldc = 64.
// ---------------------------------------------------------------------------
__global__ __launch_bounds__(256) void gemm_mfma64(
    const u16* __restrict__ A, const u16* __restrict__ BT, const void* __restrict__ bias,
    float* __restrict__ Cc, const int* __restrict__ flag,
    int K, int lda, int ldbt)
{
    const int fd = flag[0];
    __shared__ u16 As[128][32];
    __shared__ u16 Bs[64][32];
    const int m0 = blockIdx.y * 128;
    const int tid = threadIdx.x;
    const int wave = tid >> 6, lane = tid & 63;
    const int q = lane >> 4, l16 = lane & 15;
    const int wm = wave * 32;

    f32x4 acc[2][4];
    #pragma unroll
    for (int i = 0; i < 2; ++i)
        #pragma unroll
        for (int j = 0; j < 4; ++j) acc[i][j] = (f32x4){0.f, 0.f, 0.f, 0.f};

    const int srow = wave * 16 + (lane >> 2);
    const int scol = (lane & 3) * 8;

    for (int k0 = 0; k0 < K; k0 += 32) {
        #pragma unroll
        for (int pass = 0; pass < 2; ++pass) {
            int row = pass * 64 + srow;
            gll16(A + (size_t)(m0 + row) * lda + k0 + scol, &As[pass * 64 + wave * 16][0]);
        }
        gll16(BT + (size_t)srow * ldbt + k0 + scol, &Bs[wave * 16][0]);
        __syncthreads();
        bf16x8 af[2], bfr[4];
        #pragma unroll
        for (int i = 0; i < 2; ++i) af[i] = *(const bf16x8*)&As[wm + i * 16 + l16][q * 8];
        #pragma unroll
        for (int j = 0; j < 4; ++j) bfr[j] = *(const bf16x8*)&Bs[j * 16 + l16][q * 8];
        #pragma unroll
        for (int i = 0; i < 2; ++i)
            #pragma unroll
            for (int j = 0; j < 4; ++j)
                acc[i][j] = __builtin_amdgcn_mfma_f32_16x16x32_bf16(af[i], bfr[j], acc[i][j], 0, 0, 0);
        __syncthreads();
    }

    #pragma unroll
    for (int i = 0; i < 2; ++i) {
        int row = m0 + wm + i * 16 + q * 4;
        #pragma unroll
        for (int j = 0; j < 4; ++j) {
            int col = j * 16 + l16;
            #pragma unroll
            for (int r = 0; r < 4; ++r)
                Cc[(size_t)(row + r) * 64 + col] = acc[i][j][r] + ldDyn(bias, col, fd);
        }
    }
}

// ---------------------------------------------------------------------------
// Softmax over L (axis=1) per (b,p) + inclusive prefix scan -> cumT (B,L+1,P)
// ---------------------------------------------------------------------------
__global__ __launch_bounds__(256) void k_softscan(
    const float* __restrict__ psc, const int* __restrict__ maskPAD,
    float* __restrict__ pAlpha, float* __restrict__ cumT)
{
    const int b = blockIdx.x >> 6;
    const int p = blockIdx.x & 63;
    const int tid = threadIdx.x;
    __shared__ float s0[1024], s1[1024];
    __shared__ float redA[4], redB[4];

    float acc[4];
    #pragma unroll
    for (int r = 0; r < 4; ++r) {
        int m = tid + r * 256;
        float a = psc[((size_t)b * LSEQ + m) * PDIM + p];
        if (maskPAD[(size_t)b * LSEQ * LSEQ + m] == 0) a = -32768.0f;
        acc[r] = a;
    }
    float mx = fmaxf(fmaxf(acc[0], acc[1]), fmaxf(acc[2], acc[3]));
    mx = wmax(mx);
    if ((tid & 63) == 0) redA[tid >> 6] = mx;
    __syncthreads();
    mx = fmaxf(fmaxf(redA[0], redA[1]), fmaxf(redA[2], redA[3]));

    float e[4], ls = 0.f;
    #pragma unroll
    for (int r = 0; r < 4; ++r) { e[r] = expf(acc[r] - mx); ls += e[r]; }
    ls = wsum(ls);
    if ((tid & 63) == 0) redB[tid >> 6] = ls;
    __syncthreads();
    float inv = 1.0f / (redB[0] + redB[1] + redB[2] + redB[3]);

    #pragma unroll
    for (int r = 0; r < 4; ++r) {
        int m = tid + r * 256;
        float pa = e[r] * inv;
        pAlpha[((size_t)b * LSEQ + m) * PDIM + p] = pa;
        s0[m] = pa;
    }
    __syncthreads();

    float* src = s0; float* dst = s1;
    for (int off = 1; off < 1024; off <<= 1) {
        #pragma unroll
        for (int r = 0; r < 4; ++r) {
            int i = tid + r * 256;
            float v = src[i];
            if (i >= off) v += src[i - off];
            dst[i] = v;
        }
        __syncthreads();
        float* t = src; src = dst; dst = t;
    }
    size_t cb = (size_t)b * (LSEQ + 1) * PDIM + p;
    if (tid == 0) cumT[cb] = 0.f;
    #pragma unroll
    for (int r = 0; r < 4; ++r) {
        int i = tid + r * 256;
        cumT[cb + (size_t)(i + 1) * PDIM] = src[i];
    }
}

// ---------------------------------------------------------------------------
// Pooling, single-read (R3 design, unchanged)
// ---------------------------------------------------------------------------
__global__ __launch_bounds__(512) void k_pool(
    const void* __restrict__ kx, const void* __restrict__ vx,
    const float* __restrict__ pAlpha, float* __restrict__ kxp, float* __restrict__ vxp,
    const int* __restrict__ flag)
{
    const int fd = flag[0];
    const int b  = blockIdx.x >> 4;
    const int m0 = (blockIdx.x & 15) * 64;
    const int c  = threadIdx.x;
    __shared__ float pach[64][64];

    for (int i = threadIdx.x; i < 64 * 16; i += 512) {
        int e = i * 4, m = e >> 6, p = e & 63;
        *(float4*)&pach[m][p] = *(const float4*)&pAlpha[((size_t)b * LSEQ + m0 + m) * PDIM + p];
    }
    __syncthreads();

    float aK[64] = {}, aV[64] = {};
    #pragma unroll 2
    for (int m = 0; m < 64; ++m) {
        size_t idx = ((size_t)b * LSEQ + m0 + m) * CDIM + c;
        float kv = ldDyn(kx, idx, fd);
        float vv = ldDyn(vx, idx, fd);
        #pragma unroll
        for (int p4 = 0; p4 < 16; ++p4) {
            float4 pa = *(const float4*)&pach[m][p4 * 4];
            aK[p4*4+0] += pa.x * kv;  aV[p4*4+0] += pa.x * vv;
            aK[p4*4+1] += pa.y * kv;  aV[p4*4+1] += pa.y * vv;
            aK[p4*4+2] += pa.z * kv;  aV[p4*4+2] += pa.z * vv;
            aK[p4*4+3] += pa.w * kv;  aV[p4*4+3] += pa.w * vv;
        }
    }
    #pragma unroll
    for (int p = 0; p < 64; ++p) {
        atomicAdd(&kxp[((size_t)b * PDIM + p) * CDIM + c], aK[p]);
        atomicAdd(&vxp[((size_t)b * PDIM + p) * CDIM + c], aV[p]);
    }
}

// ---------------------------------------------------------------------------
// Attention: block = (b, 32-l chunk), 512 threads. k[h,:,p] and v[:,c] held
// persistently in VGPRs (read once per block -> L2 traffic /32 vs 1-block-per-l).
// Per l: S in LDS (coalesced cum gathers), q.k from LDS q-tile (wave-broadcast),
// per-wave softmax over p, alpha-v via LDS broadcast.
// ---------------------------------------------------------------------------
__global__ __launch_bounds__(512, 2) void k_attn(
    u16* __restrict__ qz, const float* __restrict__ kbT, const float* __restrict__ vb,
    const float* __restrict__ cumT, const void* __restrict__ embK, const void* __restrict__ embB,
    const int* __restrict__ flag)
{
    const int fd = flag[0];
    const int b  = blockIdx.x >> 5;
    const int l0 = (blockIdx.x & 31) * LCH;
    const int tid = threadIdx.x;
    const int h = tid >> 6, p = tid & 63;

    __shared__ u16  qld[LCH * 512];       // 32 KB
    __shared__ float S[15][64];
    __shared__ float al[8][64];
    __shared__ float eK[120], eB[120];

    // persistent register tiles
    float k_reg[64], v_reg[64];
    const float* kbb = kbT + (size_t)b * 32768;
    #pragma unroll
    for (int d = 0; d < 64; ++d) k_reg[d] = kbb[(size_t)(h * 64 + d) * 64 + p];
    const float* vbb = vb + (size_t)b * 32768;
    #pragma unroll
    for (int pp = 0; pp < 64; ++pp) v_reg[pp] = vbb[(size_t)pp * 512 + tid];

    u16* qblk = qz + ((size_t)b * LSEQ + l0) * 512;
    #pragma unroll
    for (int it = 0; it < 4; ++it) {
        int i8 = it * 512 + tid;
        *(uint4*)&qld[i8 * 8] = *(const uint4*)&qblk[i8 * 8];
    }
    if (tid < 120) { eK[tid] = ldDyn(embK, tid, fd); eB[tid] = ldDyn(embB, tid, fd); }
    __syncthreads();

    const float* cb = cumT + (size_t)b * (LSEQ + 1) * PDIM;
    const int hc = tid >> 6;   // role-c head index (same as h; kept for clarity)

    for (int ll = 0; ll < LCH; ++ll) {
        const int l = l0 + ll;
        // phase 1: S[t][p] cooperative (coalesced over p)
        for (int i = tid; i < 960; i += 512) {
            int t = i >> 6, pp = i & 63;
            float s;
            if (t == 0) {
                s = cb[(size_t)(l + 1) * 64 + pp] - cb[(size_t)l * 64 + pp];
            } else {
                s = 0.f;
                int hi = l - c_dlo[t];
                int lo = l - c_dhi[t]; if (lo < 0) lo = 0;
                if (hi >= lo) s += cb[(size_t)(hi + 1) * 64 + pp] - cb[(size_t)lo * 64 + pp];
                lo = l + c_dlo[t];
                hi = l + c_dhi[t]; if (hi > 1023) hi = 1023;
                if (lo <= hi) s += cb[(size_t)(hi + 1) * 64 + pp] - cb[(size_t)lo * 64 + pp];
            }
            S[t][pp] = s;
        }
        __syncthreads();
        // phase 2 (role h,p): bias terms + q.k + softmax
        float kbm = 0.f, bbm = 0.f;
        #pragma unroll
        for (int t = 0; t < 15; ++t) {
            float sv = S[t][p];
            kbm += eK[t * 8 + h] * sv;
            bbm += eB[t * 8 + h] * sv;
        }
        float raw = 0.f;
        const u16* qrow = &qld[ll * 512 + h * 64];
        #pragma unroll
        for (int dd = 0; dd < 32; ++dd) {
            unsigned int w = *(const unsigned int*)&qrow[dd * 2];
            raw += b2f((u16)(w & 0xFFFFu)) * k_reg[dd * 2]
                 + b2f((u16)(w >> 16))     * k_reg[dd * 2 + 1];
        }
        float sc = raw * 0.125f * kbm + bbm;
        float mx = wmax(sc);
        float e  = expf(sc - mx);
        float ssum = wsum(e);
        al[h][p] = e / ssum;
        __syncthreads();
        // phase 3 (role c = tid): z[c] = sum_p v_reg[p] * al[h(c)][p]
        float z = 0.f;
        const float* arow = al[hc];
        #pragma unroll
        for (int p4 = 0; p4 < 16; ++p4) {
            float4 a4 = *(const float4*)&arow[p4 * 4];
            z += a4.x * v_reg[p4*4+0] + a4.y * v_reg[p4*4+1]
               + a4.z * v_reg[p4*4+2] + a4.w * v_reg[p4*4+3];
        }
        qblk[(size_t)ll * 512 + tid] = f2bu(z);
        __syncthreads();   // protect S and al for next iteration
    }
}

// ---------------------------------------------------------------------------
// LayerNorm: y = LN(a (+ badd)) * g + be ; optional out2 = y + bias2 (f32)
// ---------------------------------------------------------------------------
__global__ __launch_bounds__(512) void k_ln(
    const void* __restrict__ a, const u16* __restrict__ badd,
    const void* __restrict__ g, const void* __restrict__ be, const int* __restrict__ flag,
    void* __restrict__ out, float* __restrict__ out2, const void* __restrict__ bias2,
    int aKind, int outKind)
{
    const int fd = flag[0];
    const int fA = (aKind == 2) ? fd : aKind;
    const int fO = (outKind == 2) ? fd : outKind;
    const size_t row = blockIdx.x;
    const int c = threadIdx.x;
    float x = ldDyn(a, row * CDIM + c, fA);
    if (badd) x += b2f(badd[row * CDIM + c]);

    __shared__ float rA[8], rB[8];
    float s = wsum(x);
    if ((c & 63) == 0) rA[c >> 6] = s;
    __syncthreads();
    float tot = 0.f;
    #pragma unroll
    for (int w = 0; w < 8; ++w) tot += rA[w];
    float mu = tot * (1.0f / 512.0f);
    float dv = x - mu;
    float s2 = wsum(dv * dv);
    if ((c & 63) == 0) rB[c >> 6] = s2;
    __syncthreads();
    float v2 = 0.f;
    #pragma unroll
    for (int w = 0; w < 8; ++w) v2 += rB[w];
    float y = dv * rsqrtf(v2 * (1.0f / 512.0f) + 1e-5f) * ldDyn(g, c, fd) + ldDyn(be, c, fd);
    if (fO) ((float*)out)[row * CDIM + c] = y;
    else    ((u16*)out)[row * CDIM + c] = f2bu(y);
    if (out2) out2[row * CDIM + c] = y + ldDyn(bias2, c, fd);
}

// ---------------------------------------------------------------------------
extern "C" void kernel_launch(void* const* d_in, const int* in_sizes, int n_in,
                              void* d_out, int out_size, void* d_ws, size_t ws_size,
                              hipStream_t stream)
{
    (void)in_sizes; (void)n_in; (void)out_size; (void)ws_size;
    const void* qx   = d_in[0];
    const void* kx   = d_in[1];
    const void* vx   = d_in[2];
    const int*  mask = (const int*)d_in[3];
    const void* Wp   = d_in[4];
    const void* bp   = d_in[5];
    const void* WQ   = d_in[6];
    const void* bQ   = d_in[7];
    const void* WK   = d_in[8];
    const void* bK   = d_in[9];
    const void* WV   = d_in[10];
    const void* bV   = d_in[11];
    const void* WO   = d_in[12];
    const void* bO   = d_in[13];
    const void* embK = d_in[14];
    const void* embB = d_in[15];
    const void* l1g  = d_in[16];
    const void* l1b  = d_in[17];
    const void* l2g  = d_in[18];
    const void* l2b  = d_in[19];
    const void* W1   = d_in[20];
    const void* b1   = d_in[21];
    const void* W2   = d_in[22];
    const void* b2   = d_in[23];

    // workspace map (f32-element offsets); total ~109.2 MB
    float* ws     = (float*)d_ws;
    int*   flag   = (int*)d_ws;
    float* pAlpha = ws + 64;                       // 1,048,576
    float* cumT   = ws + 1048640;                  // 1,049,600 (B, L+1, P)
    float* kxp    = ws + 2098240;                  //   524,288
    float* vxp    = ws + 2622528;                  //   524,288 (contiguous after kxp)
    float* kbT    = ws + 3146816;                  //   524,288 (B, H*DK, P)
    float* vb     = ws + 3671104;                  //   524,288 (B, P, H*DK)
    float* pre2   = ws + 4195392;                  // 8,388,608
    u16*   qz     = (u16*)(ws + 12584000);         // bf16 8.4M  (q -> z -> z1)
    u16*   qxb    = (u16*)(ws + 16778304);         // bf16 8.4M  (qx, later zo)
    u16*   zo     = qxb;                           // alias after q-proj
    u16*   hch    = (u16*)(ws + 20972608);         // bf16 8.4M  (FFN hidden chunk)
    u16*   vxb    = (u16*)(ws + 25166912);         // bf16 8.4M  (vx for pScore MFMA)
    u16*   kvxb   = (u16*)(ws + 29361216);         // bf16 1.05M (kxp|vxp bf16)
    u16*   WqT    = (u16*)(ws + 29885504);         // 262,144 u16
    u16*   WoT    = (u16*)(ws + 30016576);
    u16*   W1T    = (u16*)(ws + 30147648);         // 1,048,576 u16 [2048][512]
    u16*   W2T    = (u16*)(ws + 30671936);         // 1,048,576 u16 [512][2048]
    u16*   WpT    = (u16*)(ws + 31196224);         //  32,768 u16 [64][512]
    u16*   WkT    = (u16*)(ws + 31212608);         // 262,144 u16
    u16*   WvT    = (u16*)(ws + 31343680);         // 262,144 u16 (end 31,474,752)

    const int MROW = BI * LSEQ;                    // 16384

    // 0) dtype detection; conversions; weight transposes
    k_detect<<<dim3(1), dim3(256), 0, stream>>>((const unsigned int*)qx, flag);
    k_cvt<<<dim3(MROW * CDIM / 1024), dim3(256), 0, stream>>>(qx, qxb, flag, MROW * CDIM, 2);
    k_cvt<<<dim3(MROW * CDIM / 1024), dim3(256), 0, stream>>>(vx, vxb, flag, MROW * CDIM, 2);
    k_transp<<<dim3(2, 16),  dim3(256), 0, stream>>>(Wp, WpT, flag, 512, 64);
    k_transp<<<dim3(16, 16), dim3(256), 0, stream>>>(WQ, WqT, flag, 512, 512);
    k_transp<<<dim3(16, 16), dim3(256), 0, stream>>>(WK, WkT, flag, 512, 512);
    k_transp<<<dim3(16, 16), dim3(256), 0, stream>>>(WV, WvT, flag, 512, 512);
    k_transp<<<dim3(16, 16), dim3(256), 0, stream>>>(WO, WoT, flag, 512, 512);
    k_transp<<<dim3(64, 16), dim3(256), 0, stream>>>(W1, W1T, flag, 512, 2048);
    k_transp<<<dim3(16, 64), dim3(256), 0, stream>>>(W2, W2T, flag, 2048, 512);
    hipMemsetAsync(kxp, 0, 2 * 524288 * sizeof(float), stream);   // kxp+vxp

    // 1) pScore = vx @ Wp + bp -> pAlpha (f32), MFMA 128x64 tile
    gemm_mfma64<<<dim3(1, MROW / 128), dim3(256), 0, stream>>>(
        vxb, WpT, bp, pAlpha, flag, CDIM, CDIM, CDIM);
    // 2) softmax over L + prefix scan -> pAlpha (in place), cumT
    k_softscan<<<dim3(BI * PDIM), dim3(256), 0, stream>>>(pAlpha, mask, pAlpha, cumT);
    // 3) pooling -> kxp, vxp (single-read, atomic accumulate); then -> bf16
    k_pool<<<dim3(BI * 16), dim3(512), 0, stream>>>(kx, vx, pAlpha, kxp, vxp, flag);
    k_cvt<<<dim3(1024), dim3(256), 0, stream>>>(kxp, kvxb, flag, 1048576, 1);
    // 4) projections: q -> qz (bf16); k -> kbT (f32, perm); v -> vb (f32)
    gemm_mfma<<<dim3(4, MROW / 128), dim3(256), 0, stream>>>(
        qxb, WqT, bQ, qz, flag, MROW, CDIM, CDIM, CDIM, CDIM, CDIM, 0, 0, 1, 0);
    gemm_mfma<<<dim3(4, 8), dim3(256), 0, stream>>>(
        kvxb, WkT, bK, kbT, flag, BI * PDIM, CDIM, CDIM, CDIM, CDIM, CDIM, 0, 0, 0, 1);
    gemm_mfma<<<dim3(4, 8), dim3(256), 0, stream>>>(
        kvxb + 524288, WvT, bV, vb, flag, BI * PDIM, CDIM, CDIM, CDIM, CDIM, CDIM, 0, 0, 0, 0);
    // 5) attention: z overwrites q in qz
    k_attn<<<dim3(BI * (LSEQ / LCH)), dim3(512), 0, stream>>>(
        qz, kbT, vb, cumT, embK, embB, flag);
    // 6) zo = z @ WO + bO (bf16, into qxb alias)
    gemm_mfma<<<dim3(4, MROW / 128), dim3(256), 0, stream>>>(
        qz, WoT, bO, zo, flag, MROW, CDIM, CDIM, CDIM, CDIM, CDIM, 0, 0, 1, 0);
    // 7) LN1: z1 = LN(vx + zo) -> qz (bf16) ; pre2 = z1 + b2 (f32)
    k_ln<<<dim3(MROW), dim3(512), 0, stream>>>(
        vx, zo, l1g, l1b, flag, qz, pre2, b2, 2, 0);
    // 8) FFN in 4 hidden chunks of 512
    for (int j = 0; j < 4; ++j) {
        gemm_mfma<<<dim3(4, MROW / 128), dim3(256), 0, stream>>>(
            qz, W1T + (size_t)j * 512 * 512, b1, hch, flag,
            MROW, 512, CDIM, CDIM, CDIM, 512, (size_t)j * 512, 1, 1, 0);
        gemm_mfma<<<dim3(4, MROW / 128), dim3(256), 0, stream>>>(
            hch, W2T + (size_t)j * 512, nullptr, pre2, flag,
            MROW, CDIM, 512, 512, 2048, CDIM, 0, 2, 0, 0);
    }
    // 9) LN2 -> d_out (dtype follows detection)
    k_ln<<<dim3(MROW), dim3(512), 0, stream>>>(
        pre2, nullptr, l2g, l2b, flag, d_out, nullptr, nullptr, 1, 2);
}

// Round 6
// 920.573 us; speedup vs baseline: 2.5388x; 1.1071x over previous
//
#include <hip/hip_runtime.h>
#include <hip/hip_bf16.h>

// Shapes (fixed): B=16, L=1024, C=512, P=64, H=8, DK=64, MRD=7
#define BI   16
#define LSEQ 1024
#define CDIM 512
#define PDIM 64
#define HH   8
#define DKK  64

typedef __hip_bfloat16 bf16;
typedef unsigned short u16;
typedef __attribute__((ext_vector_type(8))) short bf16x8;
typedef __attribute__((ext_vector_type(4))) float f32x4;

// rel-pos bucket boundaries: bucket t covers |l-m| in [dlo[t], dhi[t]]
__constant__ int c_dlo[15] = {0,1,2,3,4,5,6,7, 9,11,15,23,39, 71,135};
__constant__ int c_dhi[15] = {0,1,2,3,4,5,6,8,10,14,22,38,70,134,1023};

__device__ __forceinline__ float b2f(u16 u) {
    union { unsigned int i; float f; } c; c.i = ((unsigned int)u) << 16; return c.f;
}
__device__ __forceinline__ u16 f2bu(float v) {
    bf16 h = __float2bfloat16(v);
    return *(u16*)&h;
}
// dynamic-dtype loads: f=1 -> fp32, f=0 -> bf16
__device__ __forceinline__ float ldDyn(const void* p, size_t i, int f) {
    return f ? ((const float*)p)[i] : b2f(((const u16*)p)[i]);
}
__device__ __forceinline__ void ld4Dyn(const void* p, size_t i, int f, float* o) {
    if (f) { float4 v = *(const float4*)((const float*)p + i);
             o[0]=v.x; o[1]=v.y; o[2]=v.z; o[3]=v.w; }
    else   { ushort4 u = *(const ushort4*)((const u16*)p + i);
             o[0]=b2f(u.x); o[1]=b2f(u.y); o[2]=b2f(u.z); o[3]=b2f(u.w); }
}

// async global->LDS, 16B/lane; lds base wave-uniform (HW: base + lane*16)
__device__ __forceinline__ void gll16(const u16* g, u16* l) {
    __builtin_amdgcn_global_load_lds(
        (const __attribute__((address_space(1))) unsigned int*)g,
        (__attribute__((address_space(3))) unsigned int*)l,
        16, 0, 0);
}

__device__ __forceinline__ float wsum(float v) {
    #pragma unroll
    for (int o = 32; o; o >>= 1) v += __shfl_xor(v, o, 64);
    return v;
}
__device__ __forceinline__ float wmax(float v) {
    #pragma unroll
    for (int o = 32; o; o >>= 1) v = fmaxf(v, __shfl_xor(v, o, 64));
    return v;
}

// ---------------------------------------------------------------------------
// dtype detect: flag 0 = bf16, 1 = fp32
// ---------------------------------------------------------------------------
__global__ void k_detect(const unsigned int* __restrict__ qw, int* __restrict__ flag) {
    __shared__ int cnt;
    if (threadIdx.x == 0) cnt = 0;
    __syncthreads();
    int local = 0;
    for (int i = threadIdx.x; i < 4096; i += 256) {
        float fv = b2f((u16)(qw[i] & 0xFFFFu));
        float af = fabsf(fv);
        if (fv == 0.0f || (af >= 0.0009765625f && af <= 32.0f)) local++;
    }
    atomicAdd(&cnt, local);
    __syncthreads();
    if (threadIdx.x == 0) flag[0] = (cnt >= 2048) ? 0 : 1;
}

// ---------------------------------------------------------------------------
// convert -> bf16 flat; aKind: 0=bf16, 1=f32, 2=dynamic
// ---------------------------------------------------------------------------
__global__ __launch_bounds__(256) void k_cvt(
    const void* __restrict__ src, u16* __restrict__ dst, const int* __restrict__ flag,
    int n, int aKind)
{
    const int fA = (aKind == 2) ? flag[0] : aKind;
    int i = (blockIdx.x * 256 + threadIdx.x) * 4;
    if (i >= n) return;
    float t[4]; ld4Dyn(src, i, fA, t);
    ushort4 o; o.x = f2bu(t[0]); o.y = f2bu(t[1]); o.z = f2bu(t[2]); o.w = f2bu(t[3]);
    *(ushort4*)(dst + i) = o;
}

// fused 2-tensor convert (z selects pair)
__global__ __launch_bounds__(256) void k_cvt2(
    const void* __restrict__ s0, u16* __restrict__ d0,
    const void* __restrict__ s1, u16* __restrict__ d1,
    const int* __restrict__ flag, int n)
{
    const int fA = flag[0];
    const void* src = blockIdx.y ? s1 : s0;
    u16* dst = blockIdx.y ? d1 : d0;
    int i = (blockIdx.x * 256 + threadIdx.x) * 4;
    if (i >= n) return;
    float t[4]; ld4Dyn(src, i, fA, t);
    ushort4 o; o.x = f2bu(t[0]); o.y = f2bu(t[1]); o.z = f2bu(t[2]); o.w = f2bu(t[3]);
    *(ushort4*)(dst + i) = o;
}

// ---------------------------------------------------------------------------
// transpose dyn W[Kd][Nd] -> bf16 WT[Nd][Kd]
// ---------------------------------------------------------------------------
__device__ __forceinline__ void transp_core(
    const void* W, u16* WT, int fd, int Kd, int Nd, int bx, int by)
{
    __shared__ u16 t[32][33];
    const int tx = threadIdx.x & 31, ty = threadIdx.x >> 5;   // 32 x 8
    #pragma unroll
    for (int r = 0; r < 32; r += 8) {
        int k = by * 32 + ty + r, n = bx * 32 + tx;
        t[ty + r][tx] = f2bu(ldDyn(W, (size_t)k * Nd + n, fd));
    }
    __syncthreads();
    #pragma unroll
    for (int r = 0; r < 32; r += 8) {
        int n = bx * 32 + ty + r, k = by * 32 + tx;
        WT[(size_t)n * Kd + k] = t[tx][ty + r];
    }
}

__global__ __launch_bounds__(256) void k_transp(
    const void* __restrict__ W, u16* __restrict__ WT, const int* __restrict__ flag,
    int Kd, int Nd)
{
    transp_core(W, WT, flag[0], Kd, Nd, blockIdx.x, blockIdx.y);
}

// fused 4x 512x512 transpose (z selects weight)
__global__ __launch_bounds__(256) void k_transp4(
    const void* __restrict__ W0, u16* __restrict__ T0,
    const void* __restrict__ W1, u16* __restrict__ T1,
    const void* __restrict__ W2, u16* __restrict__ T2,
    const void* __restrict__ W3, u16* __restrict__ T3,
    const int* __restrict__ flag)
{
    const void* W; u16* T;
    switch (blockIdx.z) {
        case 0: W = W0; T = T0; break;
        case 1: W = W1; T = T1; break;
        case 2: W = W2; T = T2; break;
        default: W = W3; T = T3; break;
    }
    transp_core(W, T, flag[0], 512, 512, blockIdx.x, blockIdx.y);
}

// ---------------------------------------------------------------------------
// MFMA bf16 GEMM core: 128x128 tile, BK=32, 4 waves x (4x4) 16x16x32 frags.
// global_load_lds width=16 into UNPADDED [128][32] tiles.
// mode 0: C = acc+bias ; 1: C = gelu(acc+bias) ; 2: C(f32) += acc
// perm=1 (modes 0/1): write at ((m>>6)<<15)+(col<<6)+(m&63)
// ---------------------------------------------------------------------------
__device__ __forceinline__ void gemm_core(
    u16 (*As)[32], u16 (*Bs)[32],
    const u16* A, const u16* BT, const void* bias, void* Cc, int fd,
    int K, int lda, int ldbt, int ldc, size_t bOff, int mode, int outBf, int perm,
    int m0, int n0)
{
    const int tid = threadIdx.x;
    const int wave = tid >> 6, lane = tid & 63;
    const int q = lane >> 4, l16 = lane & 15;
    const int wm = (wave >> 1) * 64, wn = (wave & 1) * 64;

    f32x4 acc[4][4];
    #pragma unroll
    for (int i = 0; i < 4; ++i)
        #pragma unroll
        for (int j = 0; j < 4; ++j) acc[i][j] = (f32x4){0.f, 0.f, 0.f, 0.f};

    const int srow = wave * 16 + (lane >> 2);
    const int scol = (lane & 3) * 8;

    for (int k0 = 0; k0 < K; k0 += 32) {
        #pragma unroll
        for (int pass = 0; pass < 2; ++pass) {
            int row = pass * 64 + srow;
            gll16(A + (size_t)(m0 + row) * lda + k0 + scol, &As[pass * 64 + wave * 16][0]);
            gll16(BT + (size_t)(n0 + row) * ldbt + k0 + scol, &Bs[pass * 64 + wave * 16][0]);
        }
        __syncthreads();
        bf16x8 af[4], bfr[4];
        #pragma unroll
        for (int i = 0; i < 4; ++i) af[i] = *(const bf16x8*)&As[wm + i * 16 + l16][q * 8];
        #pragma unroll
        for (int j = 0; j < 4; ++j) bfr[j] = *(const bf16x8*)&Bs[wn + j * 16 + l16][q * 8];
        #pragma unroll
        for (int i = 0; i < 4; ++i)
            #pragma unroll
            for (int j = 0; j < 4; ++j)
                acc[i][j] = __builtin_amdgcn_mfma_f32_16x16x32_bf16(af[i], bfr[j], acc[i][j], 0, 0, 0);
        __syncthreads();
    }

    #pragma unroll
    for (int i = 0; i < 4; ++i) {
        int row = m0 + wm + i * 16 + q * 4;
        #pragma unroll
        for (int j = 0; j < 4; ++j) {
            int col = n0 + wn + j * 16 + l16;
            #pragma unroll
            for (int r = 0; r < 4; ++r) {
                float v = acc[i][j][r];
                int m = row + r;
                if (mode == 2) {
                    ((float*)Cc)[(size_t)m * ldc + col] += v;
                } else {
                    v += ldDyn(bias, bOff + col, fd);
                    if (mode == 1) v = 0.5f * v * (1.0f + erff(v * 0.70710678118654752f));
                    size_t idx = perm ? (size_t)((m >> 6) << 15) + ((size_t)col << 6) + (m & 63)
                                      : (size_t)m * ldc + col;
                    if (outBf) ((u16*)Cc)[idx] = f2bu(v);
                    else       ((float*)Cc)[idx] = v;
                }
            }
        }
    }
}

__global__ __launch_bounds__(256) void gemm_mfma(
    const u16* __restrict__ A, const u16* __restrict__ BT, const void* __restrict__ bias,
    void* __restrict__ Cc, const int* __restrict__ flag,
    int K, int lda, int ldbt, int ldc, size_t bOff, int mode, int outBf, int perm)
{
    __shared__ u16 As[128][32];
    __shared__ u16 Bs[128][32];
    gemm_core(As, Bs, A, BT, bias, Cc, flag[0], K, lda, ldbt, ldc, bOff,
              mode, outBf, perm, blockIdx.y * 128, blockIdx.x * 128);
}

// merged k/v projection: z=0 -> k (perm, u16 kbTh), z=1 -> v (plain, u16 vbh)
__global__ __launch_bounds__(256) void gemm_kv(
    const u16* __restrict__ A0, const u16* __restrict__ A1,
    const u16* __restrict__ BT0, const u16* __restrict__ BT1,
    const void* __restrict__ b0, const void* __restrict__ b1,
    void* __restrict__ C0, void* __restrict__ C1, const int* __restrict__ flag)
{
    __shared__ u16 As[128][32];
    __shared__ u16 Bs[128][32];
    const int z = blockIdx.z;
    gemm_core(As, Bs, z ? A1 : A0, z ? BT1 : BT0, z ? b1 : b0, z ? C1 : C0, flag[0],
              CDIM, CDIM, CDIM, CDIM, 0, 0, 1, z ? 0 : 1,
              blockIdx.y * 128, blockIdx.x * 128);
}

// ---------------------------------------------------------------------------
// MFMA bf16 GEMM, 128m x 64n tile (pScore): C = A @ BT^T + bias, f32, ldc=64
// ---------------------------------------------------------------------------
__global__ __launch_bounds__(256) void gemm_mfma64(
    const u16* __restrict__ A, const u16* __restrict__ BT, const void* __restrict__ bias,
    float* __restrict__ Cc, const int* __restrict__ flag,
    int K, int lda, int ldbt)
{
    const int fd = flag[0];
    __shared__ u16 As[128][32];
    __shared__ u16 Bs[64][32];
    const int m0 = blockIdx.y * 128;
    const int tid = threadIdx.x;
    const int wave = tid >> 6, lane = tid & 63;
    const int q = lane >> 4, l16 = lane & 15;
    const int wm = wave * 32;

    f32x4 acc[2][4];
    #pragma unroll
    for (int i = 0; i < 2; ++i)
        #pragma unroll
        for (int j = 0; j < 4; ++j) acc[i][j] = (f32x4){0.f, 0.f, 0.f, 0.f};

    const int srow = wave * 16 + (lane >> 2);
    const int scol = (lane & 3) * 8;

    for (int k0 = 0; k0 < K; k0 += 32) {
        #pragma unroll
        for (int pass = 0; pass < 2; ++pass) {
            int row = pass * 64 + srow;
            gll16(A + (size_t)(m0 + row) * lda + k0 + scol, &As[pass * 64 + wave * 16][0]);
        }
        gll16(BT + (size_t)srow * ldbt + k0 + scol, &Bs[wave * 16][0]);
        __syncthreads();
        bf16x8 af[2], bfr[4];
        #pragma unroll
        for (int i = 0; i < 2; ++i) af[i] = *(const bf16x8*)&As[wm + i * 16 + l16][q * 8];
        #pragma unroll
        for (int j = 0; j < 4; ++j) bfr[j] = *(const bf16x8*)&Bs[j * 16 + l16][q * 8];
        #pragma unroll
        for (int i = 0; i < 2; ++i)
            #pragma unroll
            for (int j = 0; j < 4; ++j)
                acc[i][j] = __builtin_amdgcn_mfma_f32_16x16x32_bf16(af[i], bfr[j], acc[i][j], 0, 0, 0);
        __syncthreads();
    }

    #pragma unroll
    for (int i = 0; i < 2; ++i) {
        int row = m0 + wm + i * 16 + q * 4;
        #pragma unroll
        for (int j = 0; j < 4; ++j) {
            int col = j * 16 + l16;
            #pragma unroll
            for (int r = 0; r < 4; ++r)
                Cc[(size_t)(row + r) * 64 + col] = acc[i][j][r] + ldDyn(bias, col, fd);
        }
    }
}

// ---------------------------------------------------------------------------
// Softmax over L (axis=1) per (b,p) + inclusive prefix scan -> cumT (B,L+1,P)
// ---------------------------------------------------------------------------
__global__ __launch_bounds__(256) void k_softscan(
    const float* __restrict__ psc, const int* __restrict__ maskPAD,
    float* __restrict__ pAlpha, float* __restrict__ cumT)
{
    const int b = blockIdx.x >> 6;
    const int p = blockIdx.x & 63;
    const int tid = threadIdx.x;
    __shared__ float s0[1024], s1[1024];
    __shared__ float redA[4], redB[4];

    float acc[4];
    #pragma unroll
    for (int r = 0; r < 4; ++r) {
        int m = tid + r * 256;
        float a = psc[((size_t)b * LSEQ + m) * PDIM + p];
        if (maskPAD[(size_t)b * LSEQ * LSEQ + m] == 0) a = -32768.0f;
        acc[r] = a;
    }
    float mx = fmaxf(fmaxf(acc[0], acc[1]), fmaxf(acc[2], acc[3]));
    mx = wmax(mx);
    if ((tid & 63) == 0) redA[tid >> 6] = mx;
    __syncthreads();
    mx = fmaxf(fmaxf(redA[0], redA[1]), fmaxf(redA[2], redA[3]));

    float e[4], ls = 0.f;
    #pragma unroll
    for (int r = 0; r < 4; ++r) { e[r] = expf(acc[r] - mx); ls += e[r]; }
    ls = wsum(ls);
    if ((tid & 63) == 0) redB[tid >> 6] = ls;
    __syncthreads();
    float inv = 1.0f / (redB[0] + redB[1] + redB[2] + redB[3]);

    #pragma unroll
    for (int r = 0; r < 4; ++r) {
        int m = tid + r * 256;
        float pa = e[r] * inv;
        pAlpha[((size_t)b * LSEQ + m) * PDIM + p] = pa;
        s0[m] = pa;
    }
    __syncthreads();

    float* src = s0; float* dst = s1;
    for (int off = 1; off < 1024; off <<= 1) {
        #pragma unroll
        for (int r = 0; r < 4; ++r) {
            int i = tid + r * 256;
            float v = src[i];
            if (i >= off) v += src[i - off];
            dst[i] = v;
        }
        __syncthreads();
        float* t = src; src = dst; dst = t;
    }
    size_t cb = (size_t)b * (LSEQ + 1) * PDIM + p;
    if (tid == 0) cumT[cb] = 0.f;
    #pragma unroll
    for (int r = 0; r < 4; ++r) {
        int i = tid + r * 256;
        cumT[cb + (size_t)(i + 1) * PDIM] = src[i];
    }
}

// ---------------------------------------------------------------------------
// Pooling, single-read (R3 design)
// ---------------------------------------------------------------------------
__global__ __launch_bounds__(512) void k_pool(
    const void* __restrict__ kx, const void* __restrict__ vx,
    const float* __restrict__ pAlpha, float* __restrict__ kxp, float* __restrict__ vxp,
    const int* __restrict__ flag)
{
    const int fd = flag[0];
    const int b  = blockIdx.x >> 4;
    const int m0 = (blockIdx.x & 15) * 64;
    const int c  = threadIdx.x;
    __shared__ float pach[64][64];

    for (int i = threadIdx.x; i < 64 * 16; i += 512) {
        int e = i * 4, m = e >> 6, p = e & 63;
        *(float4*)&pach[m][p] = *(const float4*)&pAlpha[((size_t)b * LSEQ + m0 + m) * PDIM + p];
    }
    __syncthreads();

    float aK[64] = {}, aV[64] = {};
    #pragma unroll 2
    for (int m = 0; m < 64; ++m) {
        size_t idx = ((size_t)b * LSEQ + m0 + m) * CDIM + c;
        float kv = ldDyn(kx, idx, fd);
        float vv = ldDyn(vx, idx, fd);
        #pragma unroll
        for (int p4 = 0; p4 < 16; ++p4) {
            float4 pa = *(const float4*)&pach[m][p4 * 4];
            aK[p4*4+0] += pa.x * kv;  aV[p4*4+0] += pa.x * vv;
            aK[p4*4+1] += pa.y * kv;  aV[p4*4+1] += pa.y * vv;
            aK[p4*4+2] += pa.z * kv;  aV[p4*4+2] += pa.z * vv;
            aK[p4*4+3] += pa.w * kv;  aV[p4*4+3] += pa.w * vv;
        }
    }
    #pragma unroll
    for (int p = 0; p < 64; ++p) {
        atomicAdd(&kxp[((size_t)b * PDIM + p) * CDIM + c], aK[p]);
        atomicAdd(&vxp[((size_t)b * PDIM + p) * CDIM + c], aV[p]);
    }
}

// ---------------------------------------------------------------------------
// Attention (R4 structure, bf16 k/v): one block per (b,l), 512 threads.
// kbTh u16 (B,H*DK,P); vbh u16 (B,P,H*DK); t<=6 buckets from pAlpha directly.
// ---------------------------------------------------------------------------
__global__ __launch_bounds__(512) void k_attn(
    u16* __restrict__ qz, const u16* __restrict__ kbTh, const u16* __restrict__ vbh,
    const float* __restrict__ cumT, const float* __restrict__ pAlpha,
    const void* __restrict__ embK, const void* __restrict__ embB,
    const int* __restrict__ flag)
{
    const int fd = flag[0];
    const int b = blockIdx.x >> 10;
    const int l = blockIdx.x & 1023;
    const int tid = threadIdx.x;
    __shared__ float qrow[CDIM];
    __shared__ float S[15][PDIM];
    __shared__ float al[HH][PDIM];
    __shared__ float eK[120], eB[120];

    const size_t rowOff = ((size_t)b * LSEQ + l) * CDIM;
    qrow[tid] = b2f(qz[rowOff + tid]);
    if (tid < 120) { eK[tid] = ldDyn(embK, tid, fd); eB[tid] = ldDyn(embB, tid, fd); }

    const float* cb  = cumT  + (size_t)b * (LSEQ + 1) * PDIM;
    const float* pAb = pAlpha + (size_t)b * LSEQ * PDIM;
    for (int idx = tid; idx < 960; idx += 512) {
        int t = idx >> 6, pp = idx & 63;
        float s;
        if (t == 0) {
            s = pAb[(size_t)l * 64 + pp];
        } else if (t <= 6) {
            s = 0.f;
            if (l - t >= 0)   s += pAb[(size_t)(l - t) * 64 + pp];
            if (l + t <= 1023) s += pAb[(size_t)(l + t) * 64 + pp];
        } else {
            s = 0.f;
            int hi = l - c_dlo[t];
            int lo = l - c_dhi[t]; if (lo < 0) lo = 0;
            if (hi >= lo) s += cb[(size_t)(hi + 1) * 64 + pp] - cb[(size_t)lo * 64 + pp];
            lo = l + c_dlo[t];
            hi = l + c_dhi[t]; if (hi > 1023) hi = 1023;
            if (lo <= hi) s += cb[(size_t)(hi + 1) * 64 + pp] - cb[(size_t)lo * 64 + pp];
        }
        S[t][pp] = s;
    }
    __syncthreads();

    const int h = tid >> 6, p = tid & 63;   // wave h, lane p
    float kbm = 0.f, bbm = 0.f;
    #pragma unroll
    for (int t = 0; t < 15; ++t) {
        float sv = S[t][p];
        kbm += eK[t * 8 + h] * sv;
        bbm += eB[t * 8 + h] * sv;
    }
    const u16* kcol = kbTh + (size_t)b * 32768 + (size_t)h * 64 * 64 + p;
    const float* qh = qrow + h * 64;
    float raw = 0.f;
    #pragma unroll 16
    for (int d = 0; d < 64; ++d) raw += qh[d] * b2f(kcol[(size_t)d * 64]);

    float sc = raw * 0.125f * kbm + bbm;
    float mx = wmax(sc);
    float e  = expf(sc - mx);
    float ssum = wsum(e);
    al[h][p] = e / ssum;
    __syncthreads();

    float z = 0.f;
    const u16* vcol = vbh + (size_t)b * 32768 + tid;
    const float* arow = al[tid >> 6];
    #pragma unroll 16
    for (int pp = 0; pp < 64; ++pp) z += arow[pp] * b2f(vcol[(size_t)pp * 512]);
    qz[rowOff + tid] = f2bu(z);
}

// ---------------------------------------------------------------------------
// LayerNorm: y = LN(a (+ badd)) * g + be ; optional out2 = y + bias2 (f32)
// ---------------------------------------------------------------------------
__global__ __launch_bounds__(512) void k_ln(
    const void* __restrict__ a, const u16* __restrict__ badd,
    const void* __restrict__ g, const void* __restrict__ be, const int* __restrict__ flag,
    void* __restrict__ out, float* __restrict__ out2, const void* __restrict__ bias2,
    int aKind, int outKind)
{
    const int fd = flag[0];
    const int fA = (aKind == 2) ? fd : aKind;
    const int fO = (outKind == 2) ? fd : outKind;
    const size_t row = blockIdx.x;
    const int c = threadIdx.x;
    float x = ldDyn(a, row * CDIM + c, fA);
    if (badd) x += b2f(badd[row * CDIM + c]);

    __shared__ float rA[8], rB[8];
    float s = wsum(x);
    if ((c & 63) == 0) rA[c >> 6] = s;
    __syncthreads();
    float tot = 0.f;
    #pragma unroll
    for (int w = 0; w < 8; ++w) tot += rA[w];
    float mu = tot * (1.0f / 512.0f);
    float dv = x - mu;
    float s2 = wsum(dv * dv);
    if ((c & 63) == 0) rB[c >> 6] = s2;
    __syncthreads();
    float v2 = 0.f;
    #pragma unroll
    for (int w = 0; w < 8; ++w) v2 += rB[w];
    float y = dv * rsqrtf(v2 * (1.0f / 512.0f) + 1e-5f) * ldDyn(g, c, fd) + ldDyn(be, c, fd);
    if (fO) ((float*)out)[row * CDIM + c] = y;
    else    ((u16*)out)[row * CDIM + c] = f2bu(y);
    if (out2) out2[row * CDIM + c] = y + ldDyn(bias2, c, fd);
}

// ---------------------------------------------------------------------------
extern "C" void kernel_launch(void* const* d_in, const int* in_sizes, int n_in,
                              void* d_out, int out_size, void* d_ws, size_t ws_size,
                              hipStream_t stream)
{
    (void)in_sizes; (void)n_in; (void)out_size; (void)ws_size;
    const void* qx   = d_in[0];
    const void* kx   = d_in[1];
    const void* vx   = d_in[2];
    const int*  mask = (const int*)d_in[3];
    const void* Wp   = d_in[4];
    const void* bp   = d_in[5];
    const void* WQ   = d_in[6];
    const void* bQ   = d_in[7];
    const void* WK   = d_in[8];
    const void* bK   = d_in[9];
    const void* WV   = d_in[10];
    const void* bV   = d_in[11];
    const void* WO   = d_in[12];
    const void* bO   = d_in[13];
    const void* embK = d_in[14];
    const void* embB = d_in[15];
    const void* l1g  = d_in[16];
    const void* l1b  = d_in[17];
    const void* l2g  = d_in[18];
    const void* l2b  = d_in[19];
    const void* W1   = d_in[20];
    const void* b1   = d_in[21];
    const void* W2   = d_in[22];
    const void* b2   = d_in[23];

    // workspace map (f32-element offsets); total ~126 MB
    float* ws     = (float*)d_ws;
    int*   flag   = (int*)d_ws;
    float* pAlpha = ws + 64;                       // 1,048,576
    float* cumT   = ws + 1048640;                  // 1,049,600 (B, L+1, P)
    float* kxp    = ws + 2098240;                  //   524,288
    float* vxp    = ws + 2622528;                  //   524,288 (contiguous)
    u16*   kbTh   = (u16*)(ws + 3146816);          // u16 524,288 (B,H*DK,P)
    u16*   vbh    = (u16*)(ws + 3671104);          // u16 524,288 (B,P,H*DK)
    float* pre2   = ws + 4195392;                  // 8,388,608
    u16*   qz     = (u16*)(ws + 12584000);         // bf16 8.4M (q -> z -> z1)
    u16*   qxb    = (u16*)(ws + 16778304);         // bf16 8.4M (qx, later zo)
    u16*   zo     = qxb;                           // alias after q-proj
    u16*   hidden = (u16*)(ws + 20972608);         // bf16 16.8M (FFN chunk 16384x1024)
    u16*   vxb    = (u16*)(ws + 25166912);         // bf16 8.4M (vx; inside hidden span, dead by FFN)
    u16*   kvxb   = (u16*)(ws + 29361216);         // bf16 1.05M (kxp|vxp bf16)
    u16*   WqT    = (u16*)(ws + 29885504);         // 262,144 u16
    u16*   WoT    = (u16*)(ws + 30016576);
    u16*   W1T    = (u16*)(ws + 30147648);         // 1,048,576 u16 [2048][512]
    u16*   W2T    = (u16*)(ws + 30671936);         // 1,048,576 u16 [512][2048]
    u16*   WpT    = (u16*)(ws + 31196224);         //  32,768 u16 [64][512]
    u16*   WkT    = (u16*)(ws + 31212608);         // 262,144 u16
    u16*   WvT    = (u16*)(ws + 31343680);         // 262,144 u16

    const int MROW = BI * LSEQ;                    // 16384

    // 0) dtype detect; fused converts; weight transposes; zero pool accum
    k_detect<<<dim3(1), dim3(256), 0, stream>>>((const unsigned int*)qx, flag);
    k_cvt2<<<dim3(MROW * CDIM / 1024, 2), dim3(256), 0, stream>>>(
        qx, qxb, vx, vxb, flag, MROW * CDIM);
    k_transp4<<<dim3(16, 16, 4), dim3(256), 0, stream>>>(
        WQ, WqT, WK, WkT, WV, WvT, WO, WoT, flag);
    k_transp<<<dim3(2, 16),  dim3(256), 0, stream>>>(Wp, WpT, flag, 512, 64);
    k_transp<<<dim3(64, 16), dim3(256), 0, stream>>>(W1, W1T, flag, 512, 2048);
    k_transp<<<dim3(16, 64), dim3(256), 0, stream>>>(W2, W2T, flag, 2048, 512);
    hipMemsetAsync(kxp, 0, 2 * 524288 * sizeof(float), stream);

    // 1) pScore = vx @ Wp + bp -> pAlpha (f32)
    gemm_mfma64<<<dim3(1, MROW / 128), dim3(256), 0, stream>>>(
        vxb, WpT, bp, pAlpha, flag, CDIM, CDIM, CDIM);
    // 2) softmax over L + prefix scan -> pAlpha (in place), cumT
    k_softscan<<<dim3(BI * PDIM), dim3(256), 0, stream>>>(pAlpha, mask, pAlpha, cumT);
    // 3) pooling -> kxp, vxp; convert to bf16
    k_pool<<<dim3(BI * 16), dim3(512), 0, stream>>>(kx, vx, pAlpha, kxp, vxp, flag);
    k_cvt<<<dim3(1024), dim3(256), 0, stream>>>(kxp, kvxb, flag, 1048576, 1);
    // 4) projections: q -> qz (bf16); k -> kbTh (u16, perm) & v -> vbh (u16) fused
    gemm_mfma<<<dim3(4, MROW / 128), dim3(256), 0, stream>>>(
        qxb, WqT, bQ, qz, flag, CDIM, CDIM, CDIM, CDIM, 0, 0, 1, 0);
    gemm_kv<<<dim3(4, 8, 2), dim3(256), 0, stream>>>(
        kvxb, kvxb + 524288, WkT, WvT, bK, bV, kbTh, vbh, flag);
    // 5) attention: z overwrites q in qz
    k_attn<<<dim3(BI * LSEQ), dim3(512), 0, stream>>>(
        qz, kbTh, vbh, cumT, pAlpha, embK, embB, flag);
    // 6) zo = z @ WO + bO (bf16, into qxb alias)
    gemm_mfma<<<dim3(4, MROW / 128), dim3(256), 0, stream>>>(
        qz, WoT, bO, zo, flag, CDIM, CDIM, CDIM, CDIM, 0, 0, 1, 0);
    // 7) LN1: z1 = LN(vx + zo) -> qz (bf16) ; pre2 = z1 + b2 (f32)
    k_ln<<<dim3(MROW), dim3(512), 0, stream>>>(
        vx, zo, l1g, l1b, flag, qz, pre2, b2, 2, 0);
    // 8) FFN in 2 hidden chunks of 1024
    for (int j = 0; j < 2; ++j) {
        gemm_mfma<<<dim3(8, MROW / 128), dim3(256), 0, stream>>>(
            qz, W1T + (size_t)j * 1024 * 512, b1, hidden, flag,
            CDIM, CDIM, CDIM, 1024, (size_t)j * 1024, 1, 1, 0);
        gemm_mfma<<<dim3(4, MROW / 128), dim3(256), 0, stream>>>(
            hidden, W2T + (size_t)j * 1024, nullptr, pre2, flag,
            1024, 1024, 2048, CDIM, 0, 2, 0, 0);
    }
    // 9) LN2 -> d_out (dtype follows detection)
    k_ln<<<dim3(MROW), dim3(512), 0, stream>>>(
        pre2, nullptr, l2g, l2b, flag, d_out, nullptr, nullptr, 1, 2);
}

// Round 7
// 785.933 us; speedup vs baseline: 2.9737x; 1.1713x over previous
//
#include <hip/hip_runtime.h>
#include <hip/hip_bf16.h>

// Shapes (fixed): B=16, L=1024, C=512, P=64, H=8, DK=64, MRD=7
#define BI   16
#define LSEQ 1024
#define CDIM 512
#define PDIM 64
#define HH   8
#define DKK  64

typedef __hip_bfloat16 bf16;
typedef unsigned short u16;
typedef __attribute__((ext_vector_type(8))) short bf16x8;
typedef __attribute__((ext_vector_type(4))) float f32x4;

// rel-pos bucket boundaries: bucket t covers |l-m| in [dlo[t], dhi[t]]
__constant__ int c_dlo[15] = {0,1,2,3,4,5,6,7, 9,11,15,23,39, 71,135};
__constant__ int c_dhi[15] = {0,1,2,3,4,5,6,8,10,14,22,38,70,134,1023};

__device__ __forceinline__ float b2f(u16 u) {
    union { unsigned int i; float f; } c; c.i = ((unsigned int)u) << 16; return c.f;
}
__device__ __forceinline__ u16 f2bu(float v) {
    bf16 h = __float2bfloat16(v);
    return *(u16*)&h;
}
// dynamic-dtype loads: f=1 -> fp32, f=0 -> bf16
__device__ __forceinline__ float ldDyn(const void* p, size_t i, int f) {
    return f ? ((const float*)p)[i] : b2f(((const u16*)p)[i]);
}
__device__ __forceinline__ void ld4Dyn(const void* p, size_t i, int f, float* o) {
    if (f) { float4 v = *(const float4*)((const float*)p + i);
             o[0]=v.x; o[1]=v.y; o[2]=v.z; o[3]=v.w; }
    else   { ushort4 u = *(const ushort4*)((const u16*)p + i);
             o[0]=b2f(u.x); o[1]=b2f(u.y); o[2]=b2f(u.z); o[3]=b2f(u.w); }
}

// async global->LDS, 16B/lane; lds base wave-uniform (HW: base + lane*16)
__device__ __forceinline__ void gll16(const u16* g, u16* l) {
    __builtin_amdgcn_global_load_lds(
        (const __attribute__((address_space(1))) unsigned int*)g,
        (__attribute__((address_space(3))) unsigned int*)l,
        16, 0, 0);
}

__device__ __forceinline__ float wsum(float v) {
    #pragma unroll
    for (int o = 32; o; o >>= 1) v += __shfl_xor(v, o, 64);
    return v;
}
__device__ __forceinline__ float wmax(float v) {
    #pragma unroll
    for (int o = 32; o; o >>= 1) v = fmaxf(v, __shfl_xor(v, o, 64));
    return v;
}

// ---------------------------------------------------------------------------
// dtype detect: flag 0 = bf16, 1 = fp32
// ---------------------------------------------------------------------------
__global__ void k_detect(const unsigned int* __restrict__ qw, int* __restrict__ flag) {
    __shared__ int cnt;
    if (threadIdx.x == 0) cnt = 0;
    __syncthreads();
    int local = 0;
    for (int i = threadIdx.x; i < 4096; i += 256) {
        float fv = b2f((u16)(qw[i] & 0xFFFFu));
        float af = fabsf(fv);
        if (fv == 0.0f || (af >= 0.0009765625f && af <= 32.0f)) local++;
    }
    atomicAdd(&cnt, local);
    __syncthreads();
    if (threadIdx.x == 0) flag[0] = (cnt >= 2048) ? 0 : 1;
}

// ---------------------------------------------------------------------------
// convert -> bf16 flat; aKind: 0=bf16, 1=f32, 2=dynamic
// ---------------------------------------------------------------------------
__global__ __launch_bounds__(256) void k_cvt(
    const void* __restrict__ src, u16* __restrict__ dst, const int* __restrict__ flag,
    int n, int aKind)
{
    const int fA = (aKind == 2) ? flag[0] : aKind;
    int i = (blockIdx.x * 256 + threadIdx.x) * 4;
    if (i >= n) return;
    float t[4]; ld4Dyn(src, i, fA, t);
    ushort4 o; o.x = f2bu(t[0]); o.y = f2bu(t[1]); o.z = f2bu(t[2]); o.w = f2bu(t[3]);
    *(ushort4*)(dst + i) = o;
}

// fused 2-tensor convert (y selects pair)
__global__ __launch_bounds__(256) void k_cvt2(
    const void* __restrict__ s0, u16* __restrict__ d0,
    const void* __restrict__ s1, u16* __restrict__ d1,
    const int* __restrict__ flag, int n)
{
    const int fA = flag[0];
    const void* src = blockIdx.y ? s1 : s0;
    u16* dst = blockIdx.y ? d1 : d0;
    int i = (blockIdx.x * 256 + threadIdx.x) * 4;
    if (i >= n) return;
    float t[4]; ld4Dyn(src, i, fA, t);
    ushort4 o; o.x = f2bu(t[0]); o.y = f2bu(t[1]); o.z = f2bu(t[2]); o.w = f2bu(t[3]);
    *(ushort4*)(dst + i) = o;
}

// ---------------------------------------------------------------------------
// transpose dyn W[Kd][Nd] -> bf16 WT[Nd][Kd]
// ---------------------------------------------------------------------------
__device__ __forceinline__ void transp_core(
    const void* W, u16* WT, int fd, int Kd, int Nd, int bx, int by)
{
    __shared__ u16 t[32][33];
    const int tx = threadIdx.x & 31, ty = threadIdx.x >> 5;   // 32 x 8
    #pragma unroll
    for (int r = 0; r < 32; r += 8) {
        int k = by * 32 + ty + r, n = bx * 32 + tx;
        t[ty + r][tx] = f2bu(ldDyn(W, (size_t)k * Nd + n, fd));
    }
    __syncthreads();
    #pragma unroll
    for (int r = 0; r < 32; r += 8) {
        int n = bx * 32 + ty + r, k = by * 32 + tx;
        WT[(size_t)n * Kd + k] = t[tx][ty + r];
    }
}

__global__ __launch_bounds__(256) void k_transp(
    const void* __restrict__ W, u16* __restrict__ WT, const int* __restrict__ flag,
    int Kd, int Nd)
{
    transp_core(W, WT, flag[0], Kd, Nd, blockIdx.x, blockIdx.y);
}

// fused 4x 512x512 transpose (z selects weight)
__global__ __launch_bounds__(256) void k_transp4(
    const void* __restrict__ W0, u16* __restrict__ T0,
    const void* __restrict__ W1, u16* __restrict__ T1,
    const void* __restrict__ W2, u16* __restrict__ T2,
    const void* __restrict__ W3, u16* __restrict__ T3,
    const int* __restrict__ flag)
{
    const void* W; u16* T;
    switch (blockIdx.z) {
        case 0: W = W0; T = T0; break;
        case 1: W = W1; T = T1; break;
        case 2: W = W2; T = T2; break;
        default: W = W3; T = T3; break;
    }
    transp_core(W, T, flag[0], 512, 512, blockIdx.x, blockIdx.y);
}

// ---------------------------------------------------------------------------
// MFMA bf16 GEMM core: 128x128 tile, BK=32, 4 waves x (4x4) 16x16x32 frags.
// global_load_lds width=16 into UNPADDED [128][32] tiles.
// mode 0: C = acc+bias ; 1: C = gelu(acc+bias) ; 2: C(f32) += acc
// perm=1 (modes 0/1): write at ((m>>6)<<15)+(col<<6)+(m&63)
// ---------------------------------------------------------------------------
__device__ __forceinline__ void gemm_core(
    u16 (*As)[32], u16 (*Bs)[32],
    const u16* A, const u16* BT, const void* bias, void* Cc, int fd,
    int K, int lda, int ldbt, int ldc, size_t bOff, int mode, int outBf, int perm,
    int m0, int n0)
{
    const int tid = threadIdx.x;
    const int wave = tid >> 6, lane = tid & 63;
    const int q = lane >> 4, l16 = lane & 15;
    const int wm = (wave >> 1) * 64, wn = (wave & 1) * 64;

    f32x4 acc[4][4];
    #pragma unroll
    for (int i = 0; i < 4; ++i)
        #pragma unroll
        for (int j = 0; j < 4; ++j) acc[i][j] = (f32x4){0.f, 0.f, 0.f, 0.f};

    const int srow = wave * 16 + (lane >> 2);
    const int scol = (lane & 3) * 8;

    for (int k0 = 0; k0 < K; k0 += 32) {
        #pragma unroll
        for (int pass = 0; pass < 2; ++pass) {
            int row = pass * 64 + srow;
            gll16(A + (size_t)(m0 + row) * lda + k0 + scol, &As[pass * 64 + wave * 16][0]);
            gll16(BT + (size_t)(n0 + row) * ldbt + k0 + scol, &Bs[pass * 64 + wave * 16][0]);
        }
        __syncthreads();
        bf16x8 af[4], bfr[4];
        #pragma unroll
        for (int i = 0; i < 4; ++i) af[i] = *(const bf16x8*)&As[wm + i * 16 + l16][q * 8];
        #pragma unroll
        for (int j = 0; j < 4; ++j) bfr[j] = *(const bf16x8*)&Bs[wn + j * 16 + l16][q * 8];
        #pragma unroll
        for (int i = 0; i < 4; ++i)
            #pragma unroll
            for (int j = 0; j < 4; ++j)
                acc[i][j] = __builtin_amdgcn_mfma_f32_16x16x32_bf16(af[i], bfr[j], acc[i][j], 0, 0, 0);
        __syncthreads();
    }

    #pragma unroll
    for (int i = 0; i < 4; ++i) {
        int row = m0 + wm + i * 16 + q * 4;
        #pragma unroll
        for (int j = 0; j < 4; ++j) {
            int col = n0 + wn + j * 16 + l16;
            #pragma unroll
            for (int r = 0; r < 4; ++r) {
                float v = acc[i][j][r];
                int m = row + r;
                if (mode == 2) {
                    ((float*)Cc)[(size_t)m * ldc + col] += v;
                } else {
                    v += ldDyn(bias, bOff + col, fd);
                    if (mode == 1) v = 0.5f * v * (1.0f + erff(v * 0.70710678118654752f));
                    size_t idx = perm ? (size_t)((m >> 6) << 15) + ((size_t)col << 6) + (m & 63)
                                      : (size_t)m * ldc + col;
                    if (outBf) ((u16*)Cc)[idx] = f2bu(v);
                    else       ((float*)Cc)[idx] = v;
                }
            }
        }
    }
}

__global__ __launch_bounds__(256) void gemm_mfma(
    const u16* __restrict__ A, const u16* __restrict__ BT, const void* __restrict__ bias,
    void* __restrict__ Cc, const int* __restrict__ flag,
    int K, int lda, int ldbt, int ldc, size_t bOff, int mode, int outBf, int perm)
{
    __shared__ u16 As[128][32];
    __shared__ u16 Bs[128][32];
    gemm_core(As, Bs, A, BT, bias, Cc, flag[0], K, lda, ldbt, ldc, bOff,
              mode, outBf, perm, blockIdx.y * 128, blockIdx.x * 128);
}

// merged k/v projection (bf16 out): z=0 -> k plain (B,P,C); z=1 -> v perm (B,C,P)
__global__ __launch_bounds__(256) void gemm_kv(
    const u16* __restrict__ A0, const u16* __restrict__ A1,
    const u16* __restrict__ BT0, const u16* __restrict__ BT1,
    const void* __restrict__ b0, const void* __restrict__ b1,
    void* __restrict__ C0, void* __restrict__ C1, const int* __restrict__ flag)
{
    __shared__ u16 As[128][32];
    __shared__ u16 Bs[128][32];
    const int z = blockIdx.z;
    gemm_core(As, Bs, z ? A1 : A0, z ? BT1 : BT0, z ? b1 : b0, z ? C1 : C0, flag[0],
              CDIM, CDIM, CDIM, CDIM, 0, 0, 1, z ? 1 : 0,
              blockIdx.y * 128, blockIdx.x * 128);
}

// ---------------------------------------------------------------------------
// MFMA bf16 GEMM, 128m x 64n tile (pScore): C = A @ BT^T + bias, f32, ldc=64
// ---------------------------------------------------------------------------
__global__ __launch_bounds__(256) void gemm_mfma64(
    const u16* __restrict__ A, const u16* __restrict__ BT, const void* __restrict__ bias,
    float* __restrict__ Cc, const int* __restrict__ flag,
    int K, int lda, int ldbt)
{
    const int fd = flag[0];
    __shared__ u16 As[128][32];
    __shared__ u16 Bs[64][32];
    const int m0 = blockIdx.y * 128;
    const int tid = threadIdx.x;
    const int wave = tid >> 6, lane = tid & 63;
    const int q = lane >> 4, l16 = lane & 15;
    const int wm = wave * 32;

    f32x4 acc[2][4];
    #pragma unroll
    for (int i = 0; i < 2; ++i)
        #pragma unroll
        for (int j = 0; j < 4; ++j) acc[i][j] = (f32x4){0.f, 0.f, 0.f, 0.f};

    const int srow = wave * 16 + (lane >> 2);
    const int scol = (lane & 3) * 8;

    for (int k0 = 0; k0 < K; k0 += 32) {
        #pragma unroll
        for (int pass = 0; pass < 2; ++pass) {
            int row = pass * 64 + srow;
            gll16(A + (size_t)(m0 + row) * lda + k0 + scol, &As[pass * 64 + wave * 16][0]);
        }
        gll16(BT + (size_t)srow * ldbt + k0 + scol, &Bs[wave * 16][0]);
        __syncthreads();
        bf16x8 af[2], bfr[4];
        #pragma unroll
        for (int i = 0; i < 2; ++i) af[i] = *(const bf16x8*)&As[wm + i * 16 + l16][q * 8];
        #pragma unroll
        for (int j = 0; j < 4; ++j) bfr[j] = *(const bf16x8*)&Bs[j * 16 + l16][q * 8];
        #pragma unroll
        for (int i = 0; i < 2; ++i)
            #pragma unroll
            for (int j = 0; j < 4; ++j)
                acc[i][j] = __builtin_amdgcn_mfma_f32_16x16x32_bf16(af[i], bfr[j], acc[i][j], 0, 0, 0);
        __syncthreads();
    }

    #pragma unroll
    for (int i = 0; i < 2; ++i) {
        int row = m0 + wm + i * 16 + q * 4;
        #pragma unroll
        for (int j = 0; j < 4; ++j) {
            int col = j * 16 + l16;
            #pragma unroll
            for (int r = 0; r < 4; ++r)
                Cc[(size_t)(row + r) * 64 + col] = acc[i][j][r] + ldDyn(bias, col, fd);
        }
    }
}

// ---------------------------------------------------------------------------
// Attention GEMMs, batched per (b,h): 128m x 64n, K=64, 4 waves stacked in m.
// mode 0: raw[bh,l,p] = 0.125 * (q_h @ k_h^T)   (A=qz lda=512, B=kbh ldb=512)
// mode 1: z[b,l,h*64+d] = alpha_h @ v_h^T        (A=albuf lda=64, B=vbT ldb=64)
// ---------------------------------------------------------------------------
__global__ __launch_bounds__(256) void gemm_att(
    const u16* __restrict__ Abase, const u16* __restrict__ Bbase,
    void* __restrict__ outp, int mode)
{
    __shared__ u16 Aq[2][128][32];   // [k-half][l][k] 16 KB
    __shared__ u16 Bk[2][64][32];    // 8 KB
    const int bh = blockIdx.y;                 // b*8+h
    const int b = bh >> 3, h = bh & 7;
    const int m0 = blockIdx.x * 128;
    const int tid = threadIdx.x;
    const int wave = tid >> 6, lane = tid & 63;
    const int q = lane >> 4, l16 = lane & 15;

    const u16* Ag; const u16* Bg; int lda, ldb;
    if (mode == 0) {
        Ag = Abase + ((size_t)b * LSEQ + m0) * CDIM + h * 64;  lda = CDIM;
        Bg = Bbase + (size_t)b * 32768 + h * 64;               ldb = CDIM;
    } else {
        Ag = Abase + ((size_t)bh * LSEQ + m0) * 64;            lda = 64;
        Bg = Bbase + (size_t)b * 32768 + (size_t)h * 64 * 64;  ldb = 64;
    }

    const int srow = lane >> 2;          // wave-local row 0..15
    const int scol = (lane & 3) * 8;
    #pragma unroll
    for (int half = 0; half < 2; ++half) {
        #pragma unroll
        for (int pass = 0; pass < 2; ++pass) {
            int row = pass * 64 + wave * 16 + srow;
            gll16(Ag + (size_t)row * lda + half * 32 + scol,
                  &Aq[half][pass * 64 + wave * 16][0]);
        }
        gll16(Bg + (size_t)(wave * 16 + srow) * ldb + half * 32 + scol,
              &Bk[half][wave * 16][0]);
    }
    __syncthreads();

    f32x4 acc[2][4];
    #pragma unroll
    for (int i = 0; i < 2; ++i)
        #pragma unroll
        for (int j = 0; j < 4; ++j) acc[i][j] = (f32x4){0.f, 0.f, 0.f, 0.f};

    #pragma unroll
    for (int kk = 0; kk < 2; ++kk) {
        bf16x8 af[2], bfr[4];
        #pragma unroll
        for (int i = 0; i < 2; ++i)
            af[i] = *(const bf16x8*)&Aq[kk][wave * 32 + i * 16 + l16][q * 8];
        #pragma unroll
        for (int j = 0; j < 4; ++j)
            bfr[j] = *(const bf16x8*)&Bk[kk][j * 16 + l16][q * 8];
        #pragma unroll
        for (int i = 0; i < 2; ++i)
            #pragma unroll
            for (int j = 0; j < 4; ++j)
                acc[i][j] = __builtin_amdgcn_mfma_f32_16x16x32_bf16(af[i], bfr[j], acc[i][j], 0, 0, 0);
    }

    #pragma unroll
    for (int i = 0; i < 2; ++i) {
        int row = m0 + wave * 32 + i * 16 + q * 4;
        #pragma unroll
        for (int j = 0; j < 4; ++j) {
            int col = j * 16 + l16;
            #pragma unroll
            for (int r = 0; r < 4; ++r) {
                if (mode == 0) {
                    ((float*)outp)[((size_t)bh * LSEQ + row + r) * 64 + col] =
                        0.125f * acc[i][j][r];
                } else {
                    ((u16*)outp)[((size_t)b * LSEQ + row + r) * CDIM + h * 64 + col] =
                        f2bu(acc[i][j][r]);
                }
            }
        }
    }
}

// ---------------------------------------------------------------------------
// Softmax over L (axis=1) per (b,p) + inclusive prefix scan -> cumT (B,L+1,P)
// ---------------------------------------------------------------------------
__global__ __launch_bounds__(256) void k_softscan(
    const float* __restrict__ psc, const int* __restrict__ maskPAD,
    float* __restrict__ pAlpha, float* __restrict__ cumT)
{
    const int b = blockIdx.x >> 6;
    const int p = blockIdx.x & 63;
    const int tid = threadIdx.x;
    __shared__ float s0[1024], s1[1024];
    __shared__ float redA[4], redB[4];

    float acc[4];
    #pragma unroll
    for (int r = 0; r < 4; ++r) {
        int m = tid + r * 256;
        float a = psc[((size_t)b * LSEQ + m) * PDIM + p];
        if (maskPAD[(size_t)b * LSEQ * LSEQ + m] == 0) a = -32768.0f;
        acc[r] = a;
    }
    float mx = fmaxf(fmaxf(acc[0], acc[1]), fmaxf(acc[2], acc[3]));
    mx = wmax(mx);
    if ((tid & 63) == 0) redA[tid >> 6] = mx;
    __syncthreads();
    mx = fmaxf(fmaxf(redA[0], redA[1]), fmaxf(redA[2], redA[3]));

    float e[4], ls = 0.f;
    #pragma unroll
    for (int r = 0; r < 4; ++r) { e[r] = expf(acc[r] - mx); ls += e[r]; }
    ls = wsum(ls);
    if ((tid & 63) == 0) redB[tid >> 6] = ls;
    __syncthreads();
    float inv = 1.0f / (redB[0] + redB[1] + redB[2] + redB[3]);

    #pragma unroll
    for (int r = 0; r < 4; ++r) {
        int m = tid + r * 256;
        float pa = e[r] * inv;
        pAlpha[((size_t)b * LSEQ + m) * PDIM + p] = pa;
        s0[m] = pa;
    }
    __syncthreads();

    float* src = s0; float* dst = s1;
    for (int off = 1; off < 1024; off <<= 1) {
        #pragma unroll
        for (int r = 0; r < 4; ++r) {
            int i = tid + r * 256;
            float v = src[i];
            if (i >= off) v += src[i - off];
            dst[i] = v;
        }
        __syncthreads();
        float* t = src; src = dst; dst = t;
    }
    size_t cb = (size_t)b * (LSEQ + 1) * PDIM + p;
    if (tid == 0) cumT[cb] = 0.f;
    #pragma unroll
    for (int r = 0; r < 4; ++r) {
        int i = tid + r * 256;
        cumT[cb + (size_t)(i + 1) * PDIM] = src[i];
    }
}

// ---------------------------------------------------------------------------
// Pooling, single-read (R3 design)
// ---------------------------------------------------------------------------
__global__ __launch_bounds__(512) void k_pool(
    const void* __restrict__ kx, const void* __restrict__ vx,
    const float* __restrict__ pAlpha, float* __restrict__ kxp, float* __restrict__ vxp,
    const int* __restrict__ flag)
{
    const int fd = flag[0];
    const int b  = blockIdx.x >> 4;
    const int m0 = (blockIdx.x & 15) * 64;
    const int c  = threadIdx.x;
    __shared__ float pach[64][64];

    for (int i = threadIdx.x; i < 64 * 16; i += 512) {
        int e = i * 4, m = e >> 6, p = e & 63;
        *(float4*)&pach[m][p] = *(const float4*)&pAlpha[((size_t)b * LSEQ + m0 + m) * PDIM + p];
    }
    __syncthreads();

    float aK[64] = {}, aV[64] = {};
    #pragma unroll 2
    for (int m = 0; m < 64; ++m) {
        size_t idx = ((size_t)b * LSEQ + m0 + m) * CDIM + c;
        float kv = ldDyn(kx, idx, fd);
        float vv = ldDyn(vx, idx, fd);
        #pragma unroll
        for (int p4 = 0; p4 < 16; ++p4) {
            float4 pa = *(const float4*)&pach[m][p4 * 4];
            aK[p4*4+0] += pa.x * kv;  aV[p4*4+0] += pa.x * vv;
            aK[p4*4+1] += pa.y * kv;  aV[p4*4+1] += pa.y * vv;
            aK[p4*4+2] += pa.z * kv;  aV[p4*4+2] += pa.z * vv;
            aK[p4*4+3] += pa.w * kv;  aV[p4*4+3] += pa.w * vv;
        }
    }
    #pragma unroll
    for (int p = 0; p < 64; ++p) {
        atomicAdd(&kxp[((size_t)b * PDIM + p) * CDIM + c], aK[p]);
        atomicAdd(&vxp[((size_t)b * PDIM + p) * CDIM + c], aV[p]);
    }
}

// ---------------------------------------------------------------------------
// Softmax+bias middle kernel: one block per (b,l), 512 threads = (h,p).
// sc = raw*Kb + bb (raw pre-scaled by 0.125); wave softmax over p; alpha bf16.
// ---------------------------------------------------------------------------
__global__ __launch_bounds__(512) void k_sm(
    const float* __restrict__ raw, u16* __restrict__ alb,
    const float* __restrict__ cumT,
    const void* __restrict__ embK, const void* __restrict__ embB,
    const int* __restrict__ flag)
{
    const int fd = flag[0];
    const int b = blockIdx.x >> 10;
    const int l = blockIdx.x & 1023;
    const int tid = threadIdx.x;
    __shared__ float S[15][PDIM];
    __shared__ float eK[120], eB[120];

    if (tid < 120) { eK[tid] = ldDyn(embK, tid, fd); eB[tid] = ldDyn(embB, tid, fd); }

    const float* cb = cumT + (size_t)b * (LSEQ + 1) * PDIM;
    for (int idx = tid; idx < 960; idx += 512) {
        int t = idx >> 6, pp = idx & 63;
        float s;
        if (t == 0) {
            s = cb[(size_t)(l + 1) * 64 + pp] - cb[(size_t)l * 64 + pp];
        } else {
            s = 0.f;
            int hi = l - c_dlo[t];
            int lo = l - c_dhi[t]; if (lo < 0) lo = 0;
            if (hi >= lo) s += cb[(size_t)(hi + 1) * 64 + pp] - cb[(size_t)lo * 64 + pp];
            lo = l + c_dlo[t];
            hi = l + c_dhi[t]; if (hi > 1023) hi = 1023;
            if (lo <= hi) s += cb[(size_t)(hi + 1) * 64 + pp] - cb[(size_t)lo * 64 + pp];
        }
        S[t][pp] = s;
    }
    __syncthreads();

    const int h = tid >> 6, p = tid & 63;   // wave h, lane p
    float kbm = 0.f, bbm = 0.f;
    #pragma unroll
    for (int t = 0; t < 15; ++t) {
        float sv = S[t][p];
        kbm += eK[t * 8 + h] * sv;
        bbm += eB[t * 8 + h] * sv;
    }
    size_t idx = (((size_t)b * 8 + h) * LSEQ + l) * 64 + p;
    float sc = raw[idx] * kbm + bbm;
    float mx = wmax(sc);
    float e  = expf(sc - mx);
    float ssum = wsum(e);
    alb[idx] = f2bu(e / ssum);
}

// ---------------------------------------------------------------------------
// LayerNorm: y = LN(a (+ badd)) * g + be ; optional out2 = y + bias2 (f32)
// ---------------------------------------------------------------------------
__global__ __launch_bounds__(512) void k_ln(
    const void* __restrict__ a, const u16* __restrict__ badd,
    const void* __restrict__ g, const void* __restrict__ be, const int* __restrict__ flag,
    void* __restrict__ out, float* __restrict__ out2, const void* __restrict__ bias2,
    int aKind, int outKind)
{
    const int fd = flag[0];
    const int fA = (aKind == 2) ? fd : aKind;
    const int fO = (outKind == 2) ? fd : outKind;
    const size_t row = blockIdx.x;
    const int c = threadIdx.x;
    float x = ldDyn(a, row * CDIM + c, fA);
    if (badd) x += b2f(badd[row * CDIM + c]);

    __shared__ float rA[8], rB[8];
    float s = wsum(x);
    if ((c & 63) == 0) rA[c >> 6] = s;
    __syncthreads();
    float tot = 0.f;
    #pragma unroll
    for (int w = 0; w < 8; ++w) tot += rA[w];
    float mu = tot * (1.0f / 512.0f);
    float dv = x - mu;
    float s2 = wsum(dv * dv);
    if ((c & 63) == 0) rB[c >> 6] = s2;
    __syncthreads();
    float v2 = 0.f;
    #pragma unroll
    for (int w = 0; w < 8; ++w) v2 += rB[w];
    float y = dv * rsqrtf(v2 * (1.0f / 512.0f) + 1e-5f) * ldDyn(g, c, fd) + ldDyn(be, c, fd);
    if (fO) ((float*)out)[row * CDIM + c] = y;
    else    ((u16*)out)[row * CDIM + c] = f2bu(y);
    if (out2) out2[row * CDIM + c] = y + ldDyn(bias2, c, fd);
}

// ---------------------------------------------------------------------------
extern "C" void kernel_launch(void* const* d_in, const int* in_sizes, int n_in,
                              void* d_out, int out_size, void* d_ws, size_t ws_size,
                              hipStream_t stream)
{
    (void)in_sizes; (void)n_in; (void)out_size; (void)ws_size;
    const void* qx   = d_in[0];
    const void* kx   = d_in[1];
    const void* vx   = d_in[2];
    const int*  mask = (const int*)d_in[3];
    const void* Wp   = d_in[4];
    const void* bp   = d_in[5];
    const void* WQ   = d_in[6];
    const void* bQ   = d_in[7];
    const void* WK   = d_in[8];
    const void* bK   = d_in[9];
    const void* WV   = d_in[10];
    const void* bV   = d_in[11];
    const void* WO   = d_in[12];
    const void* bO   = d_in[13];
    const void* embK = d_in[14];
    const void* embB = d_in[15];
    const void* l1g  = d_in[16];
    const void* l1b  = d_in[17];
    const void* l2g  = d_in[18];
    const void* l2b  = d_in[19];
    const void* W1   = d_in[20];
    const void* b1   = d_in[21];
    const void* W2   = d_in[22];
    const void* b2   = d_in[23];

    // workspace map (f32-element offsets); total ~126 MB
    float* ws     = (float*)d_ws;
    int*   flag   = (int*)d_ws;
    float* pAlpha = ws + 64;                       // 1,048,576
    float* cumT   = ws + 1048640;                  // 1,049,600 (B, L+1, P)
    float* kxp    = ws + 2098240;                  //   524,288
    float* vxp    = ws + 2622528;                  //   524,288 (contiguous)
    u16*   kbh    = (u16*)(ws + 3146816);          // u16 524,288 (B,P,C) k-proj
    u16*   vbT    = (u16*)(ws + 3671104);          // u16 524,288 (B,C,P) v-proj
    float* pre2   = ws + 4195392;                  // 8,388,608 (rawbuf alias pre-LN1)
    float* rawbuf = pre2;                          // (B,H,L,P) f32, dead before LN1
    u16*   qz     = (u16*)(ws + 12584000);         // bf16 8.4M (q -> z -> z1)
    u16*   qxb    = (u16*)(ws + 16778304);         // bf16 8.4M (qx, later zo)
    u16*   zo     = qxb;                           // alias after q-proj
    u16*   hidden = (u16*)(ws + 20972608);         // bf16 16.8M (FFN chunk 16384x1024)
    u16*   albuf  = hidden;                        // (B,H,L,P) bf16, dead before FFN
    u16*   vxb    = (u16*)(ws + 25166912);         // bf16 8.4M (vx; dead after pScore)
    u16*   kvxb   = (u16*)(ws + 29361216);         // bf16 1.05M (kxp|vxp bf16)
    u16*   WqT    = (u16*)(ws + 29885504);         // 262,144 u16
    u16*   WoT    = (u16*)(ws + 30016576);
    u16*   W1T    = (u16*)(ws + 30147648);         // 1,048,576 u16 [2048][512]
    u16*   W2T    = (u16*)(ws + 30671936);         // 1,048,576 u16 [512][2048]
    u16*   WpT    = (u16*)(ws + 31196224);         //  32,768 u16 [64][512]
    u16*   WkT    = (u16*)(ws + 31212608);         // 262,144 u16
    u16*   WvT    = (u16*)(ws + 31343680);         // 262,144 u16

    const int MROW = BI * LSEQ;                    // 16384

    // 0) dtype detect; fused converts; weight transposes; zero pool accum
    k_detect<<<dim3(1), dim3(256), 0, stream>>>((const unsigned int*)qx, flag);
    k_cvt2<<<dim3(MROW * CDIM / 1024, 2), dim3(256), 0, stream>>>(
        qx, qxb, vx, vxb, flag, MROW * CDIM);
    k_transp4<<<dim3(16, 16, 4), dim3(256), 0, stream>>>(
        WQ, WqT, WK, WkT, WV, WvT, WO, WoT, flag);
    k_transp<<<dim3(2, 16),  dim3(256), 0, stream>>>(Wp, WpT, flag, 512, 64);
    k_transp<<<dim3(64, 16), dim3(256), 0, stream>>>(W1, W1T, flag, 512, 2048);
    k_transp<<<dim3(16, 64), dim3(256), 0, stream>>>(W2, W2T, flag, 2048, 512);
    hipMemsetAsync(kxp, 0, 2 * 524288 * sizeof(float), stream);

    // 1) pScore = vx @ Wp + bp -> pAlpha (f32)
    gemm_mfma64<<<dim3(1, MROW / 128), dim3(256), 0, stream>>>(
        vxb, WpT, bp, pAlpha, flag, CDIM, CDIM, CDIM);
    // 2) softmax over L + prefix scan -> pAlpha (in place), cumT
    k_softscan<<<dim3(BI * PDIM), dim3(256), 0, stream>>>(pAlpha, mask, pAlpha, cumT);
    // 3) pooling -> kxp, vxp; convert to bf16
    k_pool<<<dim3(BI * 16), dim3(512), 0, stream>>>(kx, vx, pAlpha, kxp, vxp, flag);
    k_cvt<<<dim3(1024), dim3(256), 0, stream>>>(kxp, kvxb, flag, 1048576, 1);
    // 4) projections: q -> qz (bf16); k -> kbh (plain) & v -> vbT (perm) fused
    gemm_mfma<<<dim3(4, MROW / 128), dim3(256), 0, stream>>>(
        qxb, WqT, bQ, qz, flag, CDIM, CDIM, CDIM, CDIM, 0, 0, 1, 0);
    gemm_kv<<<dim3(4, 8, 2), dim3(256), 0, stream>>>(
        kvxb, kvxb + 524288, WkT, WvT, bK, bV, kbh, vbT, flag);
    // 5) attention: raw = 0.125*q@k^T -> softmax+bias -> z = alpha@v (into qz)
    gemm_att<<<dim3(8, BI * HH), dim3(256), 0, stream>>>(qz, kbh, rawbuf, 0);
    k_sm<<<dim3(BI * LSEQ), dim3(512), 0, stream>>>(
        rawbuf, albuf, cumT, embK, embB, flag);
    gemm_att<<<dim3(8, BI * HH), dim3(256), 0, stream>>>(albuf, vbT, qz, 1);
    // 6) zo = z @ WO + bO (bf16, into qxb alias)
    gemm_mfma<<<dim3(4, MROW / 128), dim3(256), 0, stream>>>(
        qz, WoT, bO, zo, flag, CDIM, CDIM, CDIM, CDIM, 0, 0, 1, 0);
    // 7) LN1: z1 = LN(vx + zo) -> qz (bf16) ; pre2 = z1 + b2 (f32)
    k_ln<<<dim3(MROW), dim3(512), 0, stream>>>(
        vx, zo, l1g, l1b, flag, qz, pre2, b2, 2, 0);
    // 8) FFN in 2 hidden chunks of 1024
    for (int j = 0; j < 2; ++j) {
        gemm_mfma<<<dim3(8, MROW / 128), dim3(256), 0, stream>>>(
            qz, W1T + (size_t)j * 1024 * 512, b1, hidden, flag,
            CDIM, CDIM, CDIM, 1024, (size_t)j * 1024, 1, 1, 0);
        gemm_mfma<<<dim3(4, MROW / 128), dim3(256), 0, stream>>>(
            hidden, W2T + (size_t)j * 1024, nullptr, pre2, flag,
            1024, 1024, 2048, CDIM, 0, 2, 0, 0);
    }
    // 9) LN2 -> d_out (dtype follows detection)
    k_ln<<<dim3(MROW), dim3(512), 0, stream>>>(
        pre2, nullptr, l2g, l2b, flag, d_out, nullptr, nullptr, 1, 2);
}